// Round 1
// baseline (8888.062 us; speedup 1.0000x reference)
//
#include <hip/hip_runtime.h>
#include <hip/hip_bf16.h>

// ============================================================================
// VisionBDHv2 forward, MI355X (gfx950). Round 8.
// R7: 7775 us. All GEMMs latency-bound (MfmaUtil 12%, VALU 13%, HBM 18%,
// conflicts 0): 2-barrier-per-K-step core pays full load latency x12 steps.
// This round: gemm256_core (T3 "minimum 2-phase" pipeline) for xs/ys/mlp/
// tokens:
//   - 256x256 tile, BK=64, 512 threads (8 waves, 2Mx4N), 128 KiB LDS
//   - double-buffered K-tiles: stage t+1 into other parity BEFORE computing
//     t; single __syncthreads per K-tile (its vmcnt(0) drain is free: loads
//     had the whole ~2.5k-cyc MFMA phase to land) -> latency paid once
//   - XOR swizzle slot^=(row&7) kept from R7 (measured 0 conflicts)
//   - mlp split-K 4->6: grid 234 wgs = 91% CU fill in one round; rawK
//     6x9.6MB = 57.8MB fits R2 exactly
// attn keeps the old BK=32 core (isolation). Slack bumped for 256-tile edge
// staging overreads (192 rows x lda).
// ============================================================================

typedef short bf16x8 __attribute__((ext_vector_type(8)));
typedef float f32x4 __attribute__((ext_vector_type(4)));
typedef unsigned short u16;

#define LN_EPS 1e-5f
#define SM_SCALE 0.044194173824159216f  /* 1/sqrt(512) */
#define TWO_PI 6.283185307179586f
#define MC 3136                          /* rows per chunk = 16*196 */

typedef __attribute__((address_space(3))) unsigned char* as3p;
typedef const __attribute__((address_space(1))) unsigned char* as1p;

__device__ __forceinline__ void gload16(const u16* g, u16* l) {
    __builtin_amdgcn_global_load_lds((as1p)(const void*)g, (as3p)(void*)l, 16, 0, 0);
}

__device__ __forceinline__ u16 f2bf(float f) {
    __hip_bfloat16 h = __float2bfloat16(f);
    return *reinterpret_cast<u16*>(&h);
}
__device__ __forceinline__ float bf2f(u16 u) {
    return __uint_as_float(((unsigned)u) << 16);
}

// ---------------------------------------------------------------------------
// block reductions (256 threads, 4 waves)
// ---------------------------------------------------------------------------
__device__ __forceinline__ float block_reduce_sum(float v, float* sm) {
    #pragma unroll
    for (int o = 32; o; o >>= 1) v += __shfl_xor(v, o);
    if ((threadIdx.x & 63) == 0) sm[threadIdx.x >> 6] = v;
    __syncthreads();
    float r = sm[0] + sm[1] + sm[2] + sm[3];
    __syncthreads();
    return r;
}

// ---------------------------------------------------------------------------
// GEMM core v4: 256x256 tile, BK=64, 512 threads (8 waves as 2Mx4N),
// double-buffered LDS (2 x [256][64] u16 per operand = 128 KiB total).
// Pipeline: stage K-tile t+1 into parity q while computing t from parity p;
// one __syncthreads per K-tile (implicit vmcnt(0) drain makes t+1 visible
// AND fences parity reuse). Swizzle: physical 16B slot s holds logical slot
// s^(row&7); staged linearly (gload_lds dest = base+lane*16B) with the
// global source column pre-swizzled (involution); ds_read applies same XOR.
// Per wave per K-tile: 24 ds_read_b128, 64 MFMA. C/D: elem i ->
// row (lane>>4)*4+i, col lane&15.
// ---------------------------------------------------------------------------
__device__ __forceinline__ void gemm256_core(const u16* __restrict__ A, int lda,
                                             const u16* __restrict__ Bt, int ldb,
                                             int ktiles, f32x4 acc[8][4],
                                             u16* lds_a, u16* lds_b) {
    const int tid = threadIdx.x;          // 0..511
    const int lane = tid & 63;
    const int wave = tid >> 6;            // 0..7
    const int wr = (wave >> 2) * 128;     // wave row origin (2 M-waves)
    const int wc = (wave & 3) * 64;       // wave col origin (4 N-waves)
    const int lr = lane & 15;
    const int lg = lane >> 4;             // logical k-slot base (0..3)
    const int srow = tid >> 3;            // staging row within 64-row group
    const int gslot = (tid & 7) ^ (srow & 7);  // pre-swizzled global col slot
    const u16* ga = A + (long)srow * lda + gslot * 8;
    const u16* gb = Bt + (long)srow * ldb + gslot * 8;
    u16* la = lds_a + tid * 8;            // linear dest: row srow, slot tid&7
    u16* lb = lds_b + tid * 8;

    // prologue: stage K-tile 0 into parity 0
    #pragma unroll
    for (int j = 0; j < 4; ++j) {
        gload16(ga + (long)(j * 64) * lda, la + j * 4096);
        gload16(gb + (long)(j * 64) * ldb, lb + j * 4096);
    }
    ga += 64; gb += 64;
    __syncthreads();                      // drains vmcnt(0): tile 0 visible

    for (int t = 0; t < ktiles; ++t) {
        const int po = (t & 1) * 16384;   // u16 offset of current parity
        const int qo = po ^ 16384;
        // stage tile t+1 into the other parity (issued before compute so
        // the end-of-tile barrier drain is ~free)
        if (t + 1 < ktiles) {
            #pragma unroll
            for (int j = 0; j < 4; ++j) {
                gload16(ga + (long)(j * 64) * lda, la + qo + j * 4096);
                gload16(gb + (long)(j * 64) * ldb, lb + qo + j * 4096);
            }
            ga += 64; gb += 64;
        }
        const u16* bufa = lds_a + po;
        const u16* bufb = lds_b + po;
        // B fragments for the whole tile (reused by both m-halves)
        bf16x8 bfr[2][4];
        #pragma unroll
        for (int kk = 0; kk < 2; ++kk)
            #pragma unroll
            for (int n = 0; n < 4; ++n) {
                int row = wc + 16 * n + lr;
                bfr[kk][n] = *(const bf16x8*)&bufb[row * 64 + (((lg + kk * 4) ^ (row & 7)) * 8)];
            }
        #pragma unroll
        for (int mh = 0; mh < 2; ++mh) {
            bf16x8 af[2][4];
            #pragma unroll
            for (int kk = 0; kk < 2; ++kk)
                #pragma unroll
                for (int m = 0; m < 4; ++m) {
                    int row = wr + mh * 64 + 16 * m + lr;
                    af[kk][m] = *(const bf16x8*)&bufa[row * 64 + (((lg + kk * 4) ^ (row & 7)) * 8)];
                }
            #pragma unroll
            for (int kk = 0; kk < 2; ++kk)
                #pragma unroll
                for (int m = 0; m < 4; ++m)
                    #pragma unroll
                    for (int n = 0; n < 4; ++n)
                        acc[mh * 4 + m][n] = __builtin_amdgcn_mfma_f32_16x16x32_bf16(
                            af[kk][m], bfr[kk][n], acc[mh * 4 + m][n], 0, 0, 0);
        }
        __syncthreads();   // reads of parity po done; tile t+1 landed
    }
}

#define GEMM256_PROLOGUE                                \
    __shared__ alignas(16) u16 lds_a[2 * 256 * 64];     \
    __shared__ alignas(16) u16 lds_b[2 * 256 * 64];     \
    f32x4 acc[8][4];                                    \
    _Pragma("unroll")                                   \
    for (int m = 0; m < 8; m++)                         \
        _Pragma("unroll")                               \
        for (int n = 0; n < 4; n++)                     \
            acc[m][n] = (f32x4){0.f, 0.f, 0.f, 0.f};

#define EPI256_VARS                                     \
    const int lane = threadIdx.x & 63;                  \
    const int wave = threadIdx.x >> 6;                  \
    const int ewr = (wave >> 2) * 128 + (lane >> 4) * 4;\
    const int ewc = (wave & 3) * 64 + (lane & 15);

// ---------------------------------------------------------------------------
// GEMM core v2 (BK=32, linear, 256 threads) — used by k_attn only.
// ---------------------------------------------------------------------------
__device__ __forceinline__ void gemm_core(const u16* __restrict__ A, int lda,
                                          const u16* __restrict__ Bt, int ldb,
                                          int ksteps, f32x4 acc[4][4],
                                          u16* lds_a, u16* lds_b) {
    const int tid = threadIdx.x;
    const int lane = tid & 63;
    const int wave = tid >> 6;
    const int wr = (wave >> 1) * 64;
    const int wc = (wave & 1) * 64;
    const int lr = lane & 15;
    const int lk = (lane >> 4) * 8;
    const int srow = tid >> 2;
    const int scol = (tid & 3) * 8;
    const u16* ga = A + (long)srow * lda + scol;
    const u16* gb = Bt + (long)srow * ldb + scol;
    const long ha = (long)64 * lda;
    const long hb = (long)64 * ldb;
    u16* la = lds_a + tid * 8;
    u16* lb = lds_b + tid * 8;
    for (int k0 = 0; k0 < ksteps; ++k0) {
        __syncthreads();
        gload16(ga, la);
        gload16(ga + ha, la + 2048);
        gload16(gb, lb);
        gload16(gb + hb, lb + 2048);
        ga += 32; gb += 32;
        __syncthreads();
        bf16x8 af[4], bfr[4];
        #pragma unroll
        for (int m = 0; m < 4; m++)
            af[m] = *(const bf16x8*)&lds_a[(wr + 16 * m + lr) * 32 + lk];
        #pragma unroll
        for (int n = 0; n < 4; n++)
            bfr[n] = *(const bf16x8*)&lds_b[(wc + 16 * n + lr) * 32 + lk];
        #pragma unroll
        for (int m = 0; m < 4; m++)
            #pragma unroll
            for (int n = 0; n < 4; n++)
                acc[m][n] = __builtin_amdgcn_mfma_f32_16x16x32_bf16(af[m], bfr[n], acc[m][n], 0, 0, 0);
    }
}

#define EPI_VARS                                        \
    const int lane = threadIdx.x & 63;                  \
    const int wave = threadIdx.x >> 6;                  \
    const int ewr = (wave >> 1) * 64 + (lane >> 4) * 4; \
    const int ewc = (wave & 1) * 64 + (lane & 15);

// ---------------------------------------------------------------------------
// setup kernels
// ---------------------------------------------------------------------------
__global__ __launch_bounds__(256) void k_pack_patches(const float* __restrict__ x,
                                                      u16* __restrict__ ap) {
    int idx = blockIdx.x * 256 + threadIdx.x;           // < 12544*768
    int r = idx / 768, k = idx - r * 768;
    int b = r / 196, t = r - b * 196;
    int hp = t / 14, wp = t - hp * 14;
    int c = k >> 8, rem = k & 255, p = rem >> 4, q = rem & 15;
    long src = ((long)(b * 3 + c) * 224 + hp * 16 + p) * 224 + wp * 16 + q;
    ap[idx] = f2bf(x[src]);
}

__global__ __launch_bounds__(256) void k_cast(const float* __restrict__ s,
                                              u16* __restrict__ d, int n) {
    int i = blockIdx.x * 256 + threadIdx.x;
    if (i < n) d[i] = f2bf(s[i]);
}

// src (batch, R, C) f32 -> dst (batch, C, R) bf16
__global__ __launch_bounds__(256) void k_transpose_cast(const float* __restrict__ src,
                                                        u16* __restrict__ dst,
                                                        int R, int C) {
    __shared__ float tile[32][33];
    int c0 = blockIdx.x * 32, r0 = blockIdx.y * 32;
    long base = (long)blockIdx.z * R * C;
    int i = threadIdx.x >> 5, j = threadIdx.x & 31;
    #pragma unroll
    for (int p = 0; p < 4; p++) {
        int rr = i + p * 8;
        tile[rr][j] = src[base + (long)(r0 + rr) * C + c0 + j];
    }
    __syncthreads();
    #pragma unroll
    for (int p = 0; p < 4; p++) {
        int rr = i + p * 8;
        dst[base + (long)(c0 + rr) * R + r0 + j] = f2bf(tile[j][rr]);
    }
}

__global__ __launch_bounds__(256) void k_rope_tab(const float* __restrict__ freqs,
                                                  float* __restrict__ tc,
                                                  float* __restrict__ ts) {
    int idx = blockIdx.x * 256 + threadIdx.x;           // < 196*512
    int t = idx >> 9, n = idx & 511;
    float ph = (float)t * freqs[n];
    ph = (ph - floorf(ph)) * TWO_PI;
    tc[idx] = cosf(ph);
    ts[idx] = sinf(ph);
}

// ---------------------------------------------------------------------------
// GEMM kernels (256x256 pipelined core)
// ---------------------------------------------------------------------------
// tokens = patches @ convw^T + bias + pos_embed -> h   (M=12544,K=768,N=768)
__global__ __launch_bounds__(512, 2) void k_gemm_tokens(const u16* __restrict__ ap,
                                                        const u16* __restrict__ bw,
                                                        const float* __restrict__ cb,
                                                        const float* __restrict__ pe,
                                                        float* __restrict__ hout) {
    GEMM256_PROLOGUE
    int row0 = blockIdx.x * 256, col0 = blockIdx.y * 256;
    gemm256_core(ap + (long)row0 * 768, 768, bw + (long)col0 * 768, 768, 12,
                 acc, lds_a, lds_b);
    EPI256_VARS
    #pragma unroll
    for (int m = 0; m < 8; m++)
        #pragma unroll
        for (int n = 0; n < 4; n++)
            #pragma unroll
            for (int i = 0; i < 4; i++) {
                int row = row0 + ewr + 16 * m + i;
                int col = col0 + ewc + 16 * n;
                int t = row % 196;
                hout[(long)row * 768 + col] = acc[m][n][i] + cb[col] + pe[t * 768 + col];
            }
}

// chunk: x_sparse = relu(hn@enc); qr = rope(x_sparse)  (M=3136 masked, N=6144)
// xs/qr written HEAD-MAJOR: [(head*16+bL)*196 + t][512]
__global__ __launch_bounds__(512, 2) void k_gemm_xs(const u16* __restrict__ hnb,
                                                    const u16* __restrict__ enct,
                                                    const float* __restrict__ tc,
                                                    const float* __restrict__ tsn,
                                                    u16* __restrict__ xs,
                                                    u16* __restrict__ qr) {
    GEMM256_PROLOGUE
    // XCD swizzle: grid (13,24) -> 312 wgs = 8*39 (bijective)
    int p = blockIdx.x + 13 * blockIdx.y;
    int w = (p & 7) * 39 + (p >> 3);
    int row0 = (w % 13) * 256, col0 = (w / 13) * 256;
    int head = col0 >> 9;
    gemm256_core(hnb + (long)row0 * 768, 768,
                 enct + ((long)head * 512 + (col0 & 511)) * 768, 768, 12,
                 acc, lds_a, lds_b);
    EPI256_VARS
    #pragma unroll
    for (int m = 0; m < 8; m++)
        #pragma unroll
        for (int n = 0; n < 4; n++)
            #pragma unroll
            for (int i = 0; i < 4; i++) {
                int row = row0 + ewr + 16 * m + i;   // chunk-local bL*196+t
                int col = col0 + ewc + 16 * n;
                float v = fmaxf(acc[m][n][i], 0.f);
                float pp = __shfl_xor(v, 1);         // all lanes participate
                if (row < MC) {
                    int bL = row / 196, t = row - bL * 196;
                    int nn = col & 511;
                    float cs = tc[t * 512 + nn], sn = tsn[t * 512 + nn];
                    float rot = (nn & 1) ? pp : -pp;
                    float qv = v * cs + rot * sn;
                    long o = ((long)(head * 16 + bL) * 196 + t) * 512 + nn;
                    xs[o] = f2bf(v);
                    qr[o] = f2bf(qv);
                }
            }
}

// ---------------------------------------------------------------------------
// Fused attention: one block per (row-tile 128, bh'=h*16+bL). Scores in regs
// (128x256 via acc0+acc1), in-register softmax, P bf16 in LDS [128][232]
// (cols 0..223 only; 196..223 zero pad), PV = P x hnT over 6 col-tiles.
// Uses the BK=32 core (unchanged).
// ---------------------------------------------------------------------------
__global__ __launch_bounds__(256) void k_attn(const u16* __restrict__ qr,
                                              const u16* __restrict__ hnT,
                                              u16* __restrict__ ykv) {
    __shared__ alignas(16) u16 lds_a[128 * 32];
    __shared__ alignas(16) u16 lds_b[128 * 32];
    __shared__ alignas(16) u16 Pl[128 * 232];
    __shared__ float part[2][128][2];    // [max|sum][row][wave-col-half]
    const int tid = threadIdx.x, lane = tid & 63, wave = tid >> 6;
    const int wr = (wave >> 1) * 64, wc = (wave & 1) * 64;
    const int lr = lane & 15, lk = (lane >> 4) * 8;
    const int row0 = blockIdx.x * 128, bh = blockIdx.y;  // bh = h*16+bL
    const int bL = bh & 15;
    const u16* qbase = qr + (long)bh * 196 * 512;

    f32x4 acc0[4][4], acc1[4][4];
    #pragma unroll
    for (int m = 0; m < 4; m++)
        #pragma unroll
        for (int n = 0; n < 4; n++) {
            acc0[m][n] = (f32x4){0.f, 0.f, 0.f, 0.f};
            acc1[m][n] = (f32x4){0.f, 0.f, 0.f, 0.f};
        }
    // scores: S[row, col] = Q[row0+row] . Q[col], two 128-col tiles (K=512)
    gemm_core(qbase + (long)row0 * 512, 512, qbase, 512, 16, acc0, lds_a, lds_b);
    gemm_core(qbase + (long)row0 * 512, 512, qbase + 128 * 512, 512, 16, acc1, lds_a, lds_b);

    // ---- softmax over cols (valid < 196), scale applied inside exp ----
    const int rb = wr + (lane >> 4) * 4;
    // pass 1: per-wave-half row maxes
    #pragma unroll
    for (int m = 0; m < 4; m++)
        #pragma unroll
        for (int i = 0; i < 4; i++) {
            float mx = -1e30f;
            #pragma unroll
            for (int n = 0; n < 4; n++) {
                int c0 = wc + 16 * n + lr;
                if (c0 < 196) mx = fmaxf(mx, acc0[m][n][i]);
                if (c0 + 128 < 196) mx = fmaxf(mx, acc1[m][n][i]);
            }
            #pragma unroll
            for (int o = 1; o < 16; o <<= 1) mx = fmaxf(mx, __shfl_xor(mx, o));
            if (lr == 0) part[0][rb + 16 * m + i][wave & 1] = mx;
        }
    __syncthreads();
    // pass 2: e = exp((S - rowmax)*scale), overwrite acc, partial sums
    #pragma unroll
    for (int m = 0; m < 4; m++)
        #pragma unroll
        for (int i = 0; i < 4; i++) {
            int row = rb + 16 * m + i;
            float rmx = fmaxf(part[0][row][0], part[0][row][1]);
            float s = 0.f;
            #pragma unroll
            for (int n = 0; n < 4; n++) {
                int c0 = wc + 16 * n + lr;
                float e0 = (c0 < 196) ? __expf((acc0[m][n][i] - rmx) * SM_SCALE) : 0.f;
                float e1 = (c0 + 128 < 196) ? __expf((acc1[m][n][i] - rmx) * SM_SCALE) : 0.f;
                acc0[m][n][i] = e0; acc1[m][n][i] = e1;
                s += e0 + e1;
            }
            #pragma unroll
            for (int o = 1; o < 16; o <<= 1) s += __shfl_xor(s, o);
            if (lr == 0) part[1][row][wave & 1] = s;
        }
    __syncthreads();
    // pass 3: P = e / rowsum -> LDS bf16, cols < 224 only (stride 232)
    #pragma unroll
    for (int m = 0; m < 4; m++)
        #pragma unroll
        for (int i = 0; i < 4; i++) {
            int row = rb + 16 * m + i;
            float inv = 1.f / (part[1][row][0] + part[1][row][1]);
            #pragma unroll
            for (int n = 0; n < 4; n++) {
                int c0 = wc + 16 * n + lr;
                Pl[row * 232 + c0] = f2bf(acc0[m][n][i] * inv);
                if (c0 + 128 < 224)
                    Pl[row * 232 + c0 + 128] = f2bf(acc1[m][n][i] * inv);
            }
        }
    // ---- PV: O[row, d] = sum_s P[row,s] * hnT[d][s], 6 col-tiles, K=224 ----
    const int srow = tid >> 2, scol = (tid & 3) * 8;
    for (int cd = 0; cd < 6; ++cd) {
        const u16* Bt = hnT + ((long)bL * 768 + cd * 128) * 224;
        f32x4 acc[4][4];
        #pragma unroll
        for (int m = 0; m < 4; m++)
            #pragma unroll
            for (int n = 0; n < 4; n++) acc[m][n] = (f32x4){0.f, 0.f, 0.f, 0.f};
        for (int k0 = 0; k0 < 7; ++k0) {
            __syncthreads();
            gload16(Bt + (long)srow * 224 + k0 * 32 + scol, lds_b + tid * 8);
            gload16(Bt + (long)(srow + 64) * 224 + k0 * 32 + scol, lds_b + 2048 + tid * 8);
            __syncthreads();
            bf16x8 af[4], bfr[4];
            #pragma unroll
            for (int m = 0; m < 4; m++)
                af[m] = *(const bf16x8*)&Pl[(wr + 16 * m + lr) * 232 + k0 * 32 + lk];
            #pragma unroll
            for (int n = 0; n < 4; n++)
                bfr[n] = *(const bf16x8*)&lds_b[(wc + 16 * n + lr) * 32 + lk];
            #pragma unroll
            for (int m = 0; m < 4; m++)
                #pragma unroll
                for (int n = 0; n < 4; n++)
                    acc[m][n] = __builtin_amdgcn_mfma_f32_16x16x32_bf16(af[m], bfr[n], acc[m][n], 0, 0, 0);
        }
        EPI_VARS
        #pragma unroll
        for (int m = 0; m < 4; m++)
            #pragma unroll
            for (int n = 0; n < 4; n++)
                #pragma unroll
                for (int i = 0; i < 4; i++) {
                    int trow = row0 + ewr + 16 * m + i;
                    if (trow < 196)
                        ykv[((long)bh * 196 + trow) * 768 + cd * 128 + ewc + 16 * n] =
                            f2bf(acc[m][n][i]);
                }
    }
}

// in-place LN over D of each row of yKV (order-agnostic)
__global__ __launch_bounds__(256) void k_ln_ykv(u16* __restrict__ ykv) {
    __shared__ float sm[4];
    int r = blockIdx.x, tid = threadIdx.x;
    u16* p = ykv + (long)r * 768;
    float x0 = bf2f(p[tid]), x1 = bf2f(p[tid + 256]), x2 = bf2f(p[tid + 512]);
    float mean = block_reduce_sum(x0 + x1 + x2, sm) * (1.f / 768.f);
    float d0 = x0 - mean, d1 = x1 - mean, d2 = x2 - mean;
    float var = block_reduce_sum(d0 * d0 + d1 * d1 + d2 * d2, sm) * (1.f / 768.f);
    float rs = rsqrtf(var + LN_EPS);
    p[tid] = f2bf(d0 * rs); p[tid + 256] = f2bf(d1 * rs); p[tid + 512] = f2bf(d2 * rs);
}

// y_sparse = relu(yKV @ encv); z = x_sparse*y_sparse, head-major flatten.
// HEAD-MAJOR: per h, A = ykv[h*3136 ...] contiguous M=3136; grid (13,2,12).
__global__ __launch_bounds__(512, 2) void k_gemm_ys(const u16* __restrict__ ykv,
                                                    const u16* __restrict__ encvt,
                                                    const u16* __restrict__ xs,
                                                    u16* __restrict__ z) {
    GEMM256_PROLOGUE
    // XCD swizzle: 312 wgs = 8*39 (bijective)
    int p = blockIdx.x + 13 * (blockIdx.y + 2 * blockIdx.z);
    int w = (p & 7) * 39 + (p >> 3);
    int rt = w % 13, rem = w / 13;
    int ct = rem & 1, h = rem >> 1;
    int row0 = rt * 256, col0 = ct * 256;
    gemm256_core(ykv + ((long)h * MC + row0) * 768, 768,
                 encvt + ((long)h * 512 + col0) * 768, 768, 12,
                 acc, lds_a, lds_b);
    EPI256_VARS
    #pragma unroll
    for (int m = 0; m < 8; m++)
        #pragma unroll
        for (int n = 0; n < 4; n++)
            #pragma unroll
            for (int i = 0; i < 4; i++) {
                int row = row0 + ewr + 16 * m + i;   // bL*196+t
                int col = col0 + ewc + 16 * n;       // n in 0..511
                if (row < MC) {
                    float v = fmaxf(acc[m][n][i], 0.f) *
                              bf2f(xs[((long)h * MC + row) * 512 + col]);
                    z[(long)row * 6144 + h * 512 + col] = f2bf(v);
                }
            }
}

// yMLP_raw partial s = z[:, s*1024:(s+1)*1024] @ dec[s...]  (split-K6)
__global__ __launch_bounds__(512, 2) void k_gemm_mlp(const u16* __restrict__ z,
                                                     const u16* __restrict__ dect,
                                                     float* __restrict__ rawK) {
    GEMM256_PROLOGUE
    int row0 = blockIdx.x * 256, col0 = blockIdx.y * 256, s = blockIdx.z;
    gemm256_core(z + (long)row0 * 6144 + s * 1024, 6144,
                 dect + (long)col0 * 6144 + s * 1024, 6144, 16,
                 acc, lds_a, lds_b);
    EPI256_VARS
    float* raw = rawK + (long)s * MC * 768;
    #pragma unroll
    for (int m = 0; m < 8; m++)
        #pragma unroll
        for (int n = 0; n < 4; n++)
            #pragma unroll
            for (int i = 0; i < 4; i++) {
                int row = row0 + ewr + 16 * m + i;
                int col = col0 + ewc + 16 * n;
                if (row < MC)
                    raw[(long)row * 768 + col] = acc[m][n][i];
            }
}

// ---------------------------------------------------------------------------
// per-row LN kernels
// ---------------------------------------------------------------------------
// hn = LN(h) -> hn bf16 (row-major only; hnT built by k_hnT)
__global__ __launch_bounds__(256) void k_ln1(const float* __restrict__ h,
                                             u16* __restrict__ hnb) {
    __shared__ float sm[4];
    int r = blockIdx.x, tid = threadIdx.x;
    const float* p = h + (long)r * 768;
    float x0 = p[tid], x1 = p[tid + 256], x2 = p[tid + 512];
    float mean = block_reduce_sum(x0 + x1 + x2, sm) * (1.f / 768.f);
    float d0 = x0 - mean, d1 = x1 - mean, d2 = x2 - mean;
    float var = block_reduce_sum(d0 * d0 + d1 * d1 + d2 * d2, sm) * (1.f / 768.f);
    float rs = rsqrtf(var + LN_EPS);
    long ro = (long)r * 768;
    hnb[ro + tid] = f2bf(d0 * rs);
    hnb[ro + tid + 256] = f2bf(d1 * rs);
    hnb[ro + tid + 512] = f2bf(d2 * rs);
}

// hnT[b][d][tpad224] = hnb[b*196+t][d], t-pad zero-filled. 32x32 LDS tiles.
__global__ __launch_bounds__(256) void k_hnT(const u16* __restrict__ hnb,
                                             u16* __restrict__ hnT) {
    __shared__ u16 tile[32][33];
    int t0 = blockIdx.x * 32, d0 = blockIdx.y * 32, b = blockIdx.z;
    int i = threadIdx.x >> 5, j = threadIdx.x & 31;
    #pragma unroll
    for (int p = 0; p < 4; p++) {
        int t = t0 + i + p * 8;
        tile[i + p * 8][j] = (t < 196) ? hnb[((long)b * 196 + t) * 768 + d0 + j] : (u16)0;
    }
    __syncthreads();
    #pragma unroll
    for (int p = 0; p < 4; p++) {
        int dd = i + p * 8;
        hnT[((long)b * 768 + d0 + dd) * 224 + t0 + j] = tile[j][dd];
    }
}

// h = LN(hn + LN(sum of 6 split-K partials))
__global__ __launch_bounds__(256) void k_final_h(const float* __restrict__ rawK,
                                                 const u16* __restrict__ hnb,
                                                 float* __restrict__ h) {
    __shared__ float sm[4];
    const long PS = (long)MC * 768;
    int r = blockIdx.x, tid = threadIdx.x;
    const u16* hp = hnb + (long)r * 768;
    float y0 = 0.f, y1 = 0.f, y2 = 0.f;
    #pragma unroll
    for (int s2 = 0; s2 < 6; ++s2) {
        const float* rp = rawK + s2 * PS + (long)r * 768;
        y0 += rp[tid]; y1 += rp[tid + 256]; y2 += rp[tid + 512];
    }
    float mean = block_reduce_sum(y0 + y1 + y2, sm) * (1.f / 768.f);
    float d0 = y0 - mean, d1 = y1 - mean, d2 = y2 - mean;
    float var = block_reduce_sum(d0 * d0 + d1 * d1 + d2 * d2, sm) * (1.f / 768.f);
    float rs = rsqrtf(var + LN_EPS);
    float s0 = bf2f(hp[tid]) + d0 * rs;
    float s1 = bf2f(hp[tid + 256]) + d1 * rs;
    float s2v = bf2f(hp[tid + 512]) + d2 * rs;
    mean = block_reduce_sum(s0 + s1 + s2v, sm) * (1.f / 768.f);
    d0 = s0 - mean; d1 = s1 - mean; d2 = s2v - mean;
    var = block_reduce_sum(d0 * d0 + d1 * d1 + d2 * d2, sm) * (1.f / 768.f);
    rs = rsqrtf(var + LN_EPS);
    long ro = (long)r * 768;
    h[ro + tid] = d0 * rs; h[ro + tid + 256] = d1 * rs; h[ro + tid + 512] = d2 * rs;
}

// pool stage 1: partial sums over 14-row groups -> part[b][g][768]
__global__ __launch_bounds__(256) void k_pool1(const float* __restrict__ h,
                                               float* __restrict__ part) {
    int g = blockIdx.x, b = blockIdx.y, tid = threadIdx.x;
    const float* base = h + ((long)b * 196 + g * 14) * 768;
    float a0 = 0.f, a1 = 0.f, a2 = 0.f;
    for (int t = 0; t < 14; t++) {
        const float* p = base + (long)t * 768;
        a0 += p[tid]; a1 += p[tid + 256]; a2 += p[tid + 512];
    }
    float* pp = part + ((long)b * 14 + g) * 768;
    pp[tid] = a0; pp[tid + 256] = a1; pp[tid + 512] = a2;
}

// pool stage 2: pooled = LN(sum(part)/196)
__global__ __launch_bounds__(256) void k_pool2(const float* __restrict__ part,
                                               float* __restrict__ pooled) {
    __shared__ float sm[4];
    int b = blockIdx.x, tid = threadIdx.x;
    const float* pp = part + (long)b * 14 * 768;
    float a0 = 0.f, a1 = 0.f, a2 = 0.f;
    for (int g = 0; g < 14; g++) {
        a0 += pp[g * 768 + tid]; a1 += pp[g * 768 + tid + 256]; a2 += pp[g * 768 + tid + 512];
    }
    a0 *= (1.f / 196.f); a1 *= (1.f / 196.f); a2 *= (1.f / 196.f);
    float mean = block_reduce_sum(a0 + a1 + a2, sm) * (1.f / 768.f);
    float d0 = a0 - mean, d1 = a1 - mean, d2 = a2 - mean;
    float var = block_reduce_sum(d0 * d0 + d1 * d1 + d2 * d2, sm) * (1.f / 768.f);
    float rs = rsqrtf(var + LN_EPS);
    pooled[(long)b * 768 + tid] = d0 * rs;
    pooled[(long)b * 768 + tid + 256] = d1 * rs;
    pooled[(long)b * 768 + tid + 512] = d2 * rs;
}

// out = pooled @ head_w^T + head_b.  grid (250, 64): wave w -> col 4*bx+w.
__global__ __launch_bounds__(256) void k_head(const float* __restrict__ pooled,
                                              const float* __restrict__ hw,
                                              const float* __restrict__ hb,
                                              float* __restrict__ out) {
    __shared__ float pr[768];
    int b = blockIdx.y, tid = threadIdx.x;
    pr[tid] = pooled[(long)b * 768 + tid];
    pr[tid + 256] = pooled[(long)b * 768 + tid + 256];
    pr[tid + 512] = pooled[(long)b * 768 + tid + 512];
    __syncthreads();
    int c = blockIdx.x * 4 + (tid >> 6);
    int lane = tid & 63;
    const float* wrow = hw + (long)c * 768;
    float acc = 0.f;
    #pragma unroll
    for (int k = 0; k < 768; k += 64) acc += pr[k + lane] * wrow[k + lane];
    #pragma unroll
    for (int o = 32; o; o >>= 1) acc += __shfl_xor(acc, o);
    if (lane == 0) out[(long)b * 1000 + c] = acc + hb[c];
}

// ---------------------------------------------------------------------------
extern "C" void kernel_launch(void* const* d_in, const int* in_sizes, int n_in,
                              void* d_out, int out_size, void* d_ws, size_t ws_size,
                              hipStream_t stream) {
    const float* x     = (const float*)d_in[0];
    const float* convw = (const float*)d_in[1];
    const float* convb = (const float*)d_in[2];
    const float* pe    = (const float*)d_in[3];
    const float* enc   = (const float*)d_in[4];
    const float* encv  = (const float*)d_in[5];
    const float* dec   = (const float*)d_in[6];
    const float* freqs = (const float*)d_in[7];
    const float* hw    = (const float*)d_in[8];
    const float* hbias = (const float*)d_in[9];
    float* out = (float*)d_out;

    char* W = (char*)d_ws;
    size_t off = 0;
    auto ALLOC = [&](size_t bytes) {
        size_t o = off;
        off += (bytes + 255) & ~(size_t)255;
        return o;
    };
    // persistent
    float* bh    = (float*)(W + ALLOC(38535168));            // h f32 (12544x768)
    u16*   bhnb  = (u16*)  (W + ALLOC(19267584 + 524288));   // hn bf16 (+256-tile edge slack)
    u16*   bhnT  = (u16*)  (W + ALLOC(22020096));            // hn^T bf16 (64,768,224)
    u16*   benc  = (u16*)  (W + ALLOC(9437184));             // enc^T  (12,512,768)
    u16*   bencv = (u16*)  (W + ALLOC(9437184));             // encv^T
    u16*   bdec  = (u16*)  (W + ALLOC(9437184));             // dec^T  (768,6144)
    float* btc   = (float*)(W + ALLOC(401408));              // cos (196,512)
    float* bts   = (float*)(W + ALLOC(401408));              // sin
    float* bpool = (float*)(W + ALLOC(196608));              // pooled (64,768)
    float* bpart = (float*)(W + ALLOC(2752512));             // pool partials (64,14,768)
    // chunk regions (+slack for masked edge-tile overreads: 192 rows x lda)
    char*  R1    = (char*) (W + ALLOC(38535168 + 4194304));  // qr / z (z edge: 192*12288B)
    char*  R2    = (char*) (W + ALLOC(57802752 + 524288));   // ykv / rawK (+setup patches)
    char*  R3    = (char*) (W + ALLOC(38535168 + 524288));   // xs (+setup conv_w)
    (void)ws_size; (void)in_sizes; (void)n_in; (void)out_size;
    // total ~241 MiB

    u16*   bap  = (u16*)R2;    // setup: packed patches (18.4M)
    u16*   bcw  = (u16*)R3;    // setup: conv_w bf16 (1.2M)
    u16*   qr   = (u16*)R1;    // per-chunk head-major (192hb,196,512)
    u16*   z    = (u16*)R1;    // (3136,6144)
    u16*   ykv  = (u16*)R2;    // head-major (192hb,196,768)
    float* rawK = (float*)R2;  // yMLP split-K partials 6x(3136,768) f32 = 57.8MB
    u16*   xs   = (u16*)R3;    // head-major (192hb,196,512)

    // ---- setup ----
    k_pack_patches<<<37632, 256, 0, stream>>>(x, bap);
    k_cast<<<2304, 256, 0, stream>>>(convw, bcw, 768 * 768);
    k_gemm_tokens<<<dim3(49, 3), 512, 0, stream>>>(bap, bcw, convb, pe, bh);
    k_transpose_cast<<<dim3(16, 24, 12), 256, 0, stream>>>(enc, benc, 768, 512);
    k_transpose_cast<<<dim3(16, 24, 12), 256, 0, stream>>>(encv, bencv, 768, 512);
    k_transpose_cast<<<dim3(24, 192, 1), 256, 0, stream>>>(dec, bdec, 6144, 768);
    k_rope_tab<<<392, 256, 0, stream>>>(freqs, btc, bts);

    // ---- 6 shared-weight layers, 4 chunks of 16 images each ----
    for (int L = 0; L < 6; ++L) {
        k_ln1<<<12544, 256, 0, stream>>>(bh, bhnb);
        k_hnT<<<dim3(7, 24, 64), 256, 0, stream>>>(bhnb, bhnT);
        for (int c = 0; c < 4; ++c) {
            long r0 = (long)c * MC;                    // chunk row offset
            k_gemm_xs<<<dim3(13, 24), 512, 0, stream>>>(
                bhnb + r0 * 768, benc, btc, bts, xs, qr);
            k_attn<<<dim3(2, 192), 256, 0, stream>>>(
                qr, bhnT + (long)c * 16 * 768 * 224, ykv);
            k_ln_ykv<<<37632, 256, 0, stream>>>(ykv);
            k_gemm_ys<<<dim3(13, 2, 12), 512, 0, stream>>>(ykv, bencv, xs, z);
            k_gemm_mlp<<<dim3(13, 3, 6), 512, 0, stream>>>(z, bdec, rawK);
            k_final_h<<<MC, 256, 0, stream>>>(rawK, bhnb + r0 * 768, bh + r0 * 768);
        }
    }

    // ---- head ----
    k_pool1<<<dim3(14, 64), 256, 0, stream>>>(bh, bpart);
    k_pool2<<<64, 256, 0, stream>>>(bpart, bpool);
    k_head<<<dim3(250, 64), 256, 0, stream>>>(bpool, hw, hbias, out);
}

// Round 2
// 8644.385 us; speedup vs baseline: 1.0282x; 1.0282x over previous
//
#include <hip/hip_runtime.h>
#include <hip/hip_bf16.h>

// ============================================================================
// VisionBDHv2 forward, MI355X (gfx950). Round 9.
// R7: 7775us (128x128, 2-barrier core, 5 blocks/CU, latency-bound 12% Mfma).
// R8: 8888us REGRESSION (256x256 2-phase dbuf: 1 blk/CU, vmcnt(0) drain on
//     critical path with no TLP to hide it + 2-round grid quantization).
// R9: 256x256 8-phase core (T3+T4+T5, m201 schedule) in plain HIP:
//   - 4 phases per BK=64 K-tile: {ds-read A subtile (+B at ph0 into regs) ||
//     issue 1 half-tile gload_lds -> s_barrier -> setprio(1) -> 16 MFMA ->
//     setprio(0) -> s_barrier}
//   - counted s_waitcnt vmcnt(4) ONLY at phases 4/8 (never 0 in-loop);
//     stage calendar race-audited: each stage lands >=1 barrier after the
//     last read of the region it overwrites (B freed early: consumed into
//     registers at tile phase 0)
//   - sched_barrier(0) after each vmcnt wait + its barrier (rule #18)
//   - XOR swizzle slot^=(row&7) kept (0 conflicts measured R7/R8)
// attn keeps the old BK=32 core (isolation).
// ============================================================================

typedef short bf16x8 __attribute__((ext_vector_type(8)));
typedef float f32x4 __attribute__((ext_vector_type(4)));
typedef unsigned short u16;

#define LN_EPS 1e-5f
#define SM_SCALE 0.044194173824159216f  /* 1/sqrt(512) */
#define TWO_PI 6.283185307179586f
#define MC 3136                          /* rows per chunk = 16*196 */

typedef __attribute__((address_space(3))) unsigned char* as3p;
typedef const __attribute__((address_space(1))) unsigned char* as1p;

__device__ __forceinline__ void gload16(const u16* g, u16* l) {
    __builtin_amdgcn_global_load_lds((as1p)(const void*)g, (as3p)(void*)l, 16, 0, 0);
}

__device__ __forceinline__ u16 f2bf(float f) {
    __hip_bfloat16 h = __float2bfloat16(f);
    return *reinterpret_cast<u16*>(&h);
}
__device__ __forceinline__ float bf2f(u16 u) {
    return __uint_as_float(((unsigned)u) << 16);
}

// ---------------------------------------------------------------------------
// block reductions (256 threads, 4 waves)
// ---------------------------------------------------------------------------
__device__ __forceinline__ float block_reduce_sum(float v, float* sm) {
    #pragma unroll
    for (int o = 32; o; o >>= 1) v += __shfl_xor(v, o);
    if ((threadIdx.x & 63) == 0) sm[threadIdx.x >> 6] = v;
    __syncthreads();
    float r = sm[0] + sm[1] + sm[2] + sm[3];
    __syncthreads();
    return r;
}

// ---------------------------------------------------------------------------
// GEMM core v5: 256x256 tile, BK=64, 512 threads (8 waves, 2Mx4N), 8-phase
// pipelined schedule with counted vmcnt. LDS: 2 parities x [256][64] u16 per
// operand (128 KiB). Tile t lives in parity t&1. Stage calendar per
// iteration (tiles T=2i, T+1; phase = tile-phase 0..3):
//   T.p0: A(T+1)h0   T.p1: A(T+1)h1   T.p2: B(T+2)h0   T.p3: B(T+2)h1 +W
//   U.p0: A(T+2)h0   U.p1: A(T+2)h1   U.p2: B(T+3)h0   U.p3: B(T+3)h1 +W
// (U = tile T+1; W = s_waitcnt vmcnt(4), vmcnt(0) on last iteration's T.p3).
// Legality: B(t) is read fully into registers at t's phase 0, so B(t+2) can
// be staged from t's phase 2; A(t) rows finish at t's phase 3, so A(t+2)
// stages from (t+1)'s phase 0. Completeness: at each W, everything needed
// for the next 4 phases is >= 4 loads old. Swizzle: physical 16B slot s
// holds logical s^(row&7); global source col pre-swizzled, linear LDS dest.
// ---------------------------------------------------------------------------
__device__ __forceinline__ void gemm256p(const u16* __restrict__ A, int lda,
                                         const u16* __restrict__ Bt, int ldb,
                                         int ktiles /*even, >=4*/, f32x4 acc[8][4],
                                         u16* lds_a, u16* lds_b) {
    const int tid = threadIdx.x;          // 0..511
    const int lane = tid & 63;
    const int wave = tid >> 6;            // 0..7
    const int wr = (wave >> 2) * 128;     // wave row origin (2 M-waves)
    const int wc = (wave & 3) * 64;       // wave col origin (4 N-waves)
    const int lr = lane & 15;
    const int lg = lane >> 4;             // logical k-slot base (0..3)
    const int rx = lr & 7;
    const int srow = tid >> 3;            // staging row within 64-row slab
    const int gslot = (tid & 7) ^ (srow & 7);  // pre-swizzled global col slot
    const u16* gA = A + (long)srow * lda + gslot * 8;
    const u16* gB = Bt + (long)srow * ldb + gslot * 8;
    u16* lA = lds_a + tid * 8;            // linear dest: row srow, slot tid&7
    u16* lB = lds_b + tid * 8;

// stage one half-tile (128 rows x 64 cols) of tile t, half h: 2 gload_lds
#define STG(gbase, ld, lbase, t, h)                                          \
    {                                                                        \
        const u16* gp_ = (gbase) + (long)((h) * 128) * (ld) + (t) * 64;      \
        u16* lp_ = (lbase) + ((t) & 1) * 16384 + (h) * 8192;                 \
        gload16(gp_, lp_);                                                   \
        gload16(gp_ + (long)64 * (ld), lp_ + 4096);                          \
    }

// one phase: ds-reads (B bulk at PH-first), stage slot, barrier, MFMA, barrier
#define PHASE(PAR, PH, LOADB, STGSTMT, WAITSTMT, PINSTMT)                    \
    {                                                                        \
        if (LOADB) {                                                         \
            _Pragma("unroll")                                                \
            for (int kk = 0; kk < 2; ++kk)                                   \
                _Pragma("unroll")                                            \
                for (int n = 0; n < 4; ++n)                                  \
                    bfr[kk][n] = *(const bf16x8*)&lds_b[(PAR) * 16384 +      \
                        (wc + 16 * n + lr) * 64 + (((lg + 4 * kk) ^ rx) * 8)]; \
        }                                                                    \
        bf16x8 af[2][2];                                                     \
        _Pragma("unroll")                                                    \
        for (int kk = 0; kk < 2; ++kk)                                       \
            _Pragma("unroll")                                                \
            for (int j = 0; j < 2; ++j)                                      \
                af[kk][j] = *(const bf16x8*)&lds_a[(PAR) * 16384 +           \
                    (wr + 16 * (2 * (PH) + j) + lr) * 64 +                   \
                    (((lg + 4 * kk) ^ rx) * 8)];                             \
        STGSTMT;                                                             \
        __builtin_amdgcn_s_barrier();                                        \
        __builtin_amdgcn_s_setprio(1);                                       \
        _Pragma("unroll")                                                    \
        for (int kk = 0; kk < 2; ++kk)                                       \
            _Pragma("unroll")                                                \
            for (int j = 0; j < 2; ++j)                                      \
                _Pragma("unroll")                                            \
                for (int n = 0; n < 4; ++n)                                  \
                    acc[2 * (PH) + j][n] = __builtin_amdgcn_mfma_f32_16x16x32_bf16( \
                        af[kk][j], bfr[kk][n], acc[2 * (PH) + j][n], 0, 0, 0); \
        __builtin_amdgcn_s_setprio(0);                                       \
        WAITSTMT;                                                            \
        __builtin_amdgcn_s_barrier();                                        \
        PINSTMT;                                                             \
    }

    // prologue: B(0), A(0), B(1) staged; wait leaves B(1) (4 loads) in flight
    STG(gB, ldb, lB, 0, 0); STG(gB, ldb, lB, 0, 1);
    STG(gA, lda, lA, 0, 0); STG(gA, lda, lA, 0, 1);
    STG(gB, ldb, lB, 1, 0); STG(gB, ldb, lB, 1, 1);
    asm volatile("s_waitcnt vmcnt(4)" ::: "memory");
    __builtin_amdgcn_sched_barrier(0);
    __builtin_amdgcn_s_barrier();
    __builtin_amdgcn_sched_barrier(0);

    const int iters = ktiles >> 1;
    for (int i = 0; i < iters; ++i) {
        const int T = 2 * i;
        const bool last = (i == iters - 1);
        // ---------- tile T (parity 0): phases 1-4 ----------
        {
            bf16x8 bfr[2][4];
            PHASE(0, 0, true,  STG(gA, lda, lA, T + 1, 0), , )
            PHASE(0, 1, false, STG(gA, lda, lA, T + 1, 1), , )
            PHASE(0, 2, false, if (!last) STG(gB, ldb, lB, T + 2, 0), , )
            PHASE(0, 3, false, if (!last) STG(gB, ldb, lB, T + 2, 1),
                  if (last) { asm volatile("s_waitcnt vmcnt(0)" ::: "memory"); }
                  else      { asm volatile("s_waitcnt vmcnt(4)" ::: "memory"); }
                  __builtin_amdgcn_sched_barrier(0),
                  __builtin_amdgcn_sched_barrier(0))
        }
        // ---------- tile T+1 (parity 1): phases 5-8 ----------
        {
            bf16x8 bfr[2][4];
            PHASE(1, 0, true,  if (!last) STG(gA, lda, lA, T + 2, 0), , )
            PHASE(1, 1, false, if (!last) STG(gA, lda, lA, T + 2, 1), , )
            PHASE(1, 2, false, if (!last) STG(gB, ldb, lB, T + 3, 0), , )
            PHASE(1, 3, false, if (!last) STG(gB, ldb, lB, T + 3, 1),
                  if (!last) {
                      asm volatile("s_waitcnt vmcnt(4)" ::: "memory");
                      __builtin_amdgcn_sched_barrier(0);
                  },
                  if (!last) { __builtin_amdgcn_sched_barrier(0); })
        }
    }
#undef PHASE
#undef STG
}

#define GEMM256_PROLOGUE                                \
    __shared__ alignas(16) u16 lds_a[2 * 256 * 64];     \
    __shared__ alignas(16) u16 lds_b[2 * 256 * 64];     \
    f32x4 acc[8][4];                                    \
    _Pragma("unroll")                                   \
    for (int m = 0; m < 8; m++)                         \
        _Pragma("unroll")                               \
        for (int n = 0; n < 4; n++)                     \
            acc[m][n] = (f32x4){0.f, 0.f, 0.f, 0.f};

#define EPI256_VARS                                     \
    const int lane = threadIdx.x & 63;                  \
    const int wave = threadIdx.x >> 6;                  \
    const int ewr = (wave >> 2) * 128 + (lane >> 4) * 4;\
    const int ewc = (wave & 3) * 64 + (lane & 15);

// ---------------------------------------------------------------------------
// GEMM core v2 (BK=32, linear, 256 threads) — used by k_attn only.
// ---------------------------------------------------------------------------
__device__ __forceinline__ void gemm_core(const u16* __restrict__ A, int lda,
                                          const u16* __restrict__ Bt, int ldb,
                                          int ksteps, f32x4 acc[4][4],
                                          u16* lds_a, u16* lds_b) {
    const int tid = threadIdx.x;
    const int lane = tid & 63;
    const int wave = tid >> 6;
    const int wr = (wave >> 1) * 64;
    const int wc = (wave & 1) * 64;
    const int lr = lane & 15;
    const int lk = (lane >> 4) * 8;
    const int srow = tid >> 2;
    const int scol = (tid & 3) * 8;
    const u16* ga = A + (long)srow * lda + scol;
    const u16* gb = Bt + (long)srow * ldb + scol;
    const long ha = (long)64 * lda;
    const long hb = (long)64 * ldb;
    u16* la = lds_a + tid * 8;
    u16* lb = lds_b + tid * 8;
    for (int k0 = 0; k0 < ksteps; ++k0) {
        __syncthreads();
        gload16(ga, la);
        gload16(ga + ha, la + 2048);
        gload16(gb, lb);
        gload16(gb + hb, lb + 2048);
        ga += 32; gb += 32;
        __syncthreads();
        bf16x8 af[4], bfr[4];
        #pragma unroll
        for (int m = 0; m < 4; m++)
            af[m] = *(const bf16x8*)&lds_a[(wr + 16 * m + lr) * 32 + lk];
        #pragma unroll
        for (int n = 0; n < 4; n++)
            bfr[n] = *(const bf16x8*)&lds_b[(wc + 16 * n + lr) * 32 + lk];
        #pragma unroll
        for (int m = 0; m < 4; m++)
            #pragma unroll
            for (int n = 0; n < 4; n++)
                acc[m][n] = __builtin_amdgcn_mfma_f32_16x16x32_bf16(af[m], bfr[n], acc[m][n], 0, 0, 0);
    }
}

#define EPI_VARS                                        \
    const int lane = threadIdx.x & 63;                  \
    const int wave = threadIdx.x >> 6;                  \
    const int ewr = (wave >> 1) * 64 + (lane >> 4) * 4; \
    const int ewc = (wave & 1) * 64 + (lane & 15);

// ---------------------------------------------------------------------------
// setup kernels
// ---------------------------------------------------------------------------
__global__ __launch_bounds__(256) void k_pack_patches(const float* __restrict__ x,
                                                      u16* __restrict__ ap) {
    int idx = blockIdx.x * 256 + threadIdx.x;           // < 12544*768
    int r = idx / 768, k = idx - r * 768;
    int b = r / 196, t = r - b * 196;
    int hp = t / 14, wp = t - hp * 14;
    int c = k >> 8, rem = k & 255, p = rem >> 4, q = rem & 15;
    long src = ((long)(b * 3 + c) * 224 + hp * 16 + p) * 224 + wp * 16 + q;
    ap[idx] = f2bf(x[src]);
}

__global__ __launch_bounds__(256) void k_cast(const float* __restrict__ s,
                                              u16* __restrict__ d, int n) {
    int i = blockIdx.x * 256 + threadIdx.x;
    if (i < n) d[i] = f2bf(s[i]);
}

// src (batch, R, C) f32 -> dst (batch, C, R) bf16
__global__ __launch_bounds__(256) void k_transpose_cast(const float* __restrict__ src,
                                                        u16* __restrict__ dst,
                                                        int R, int C) {
    __shared__ float tile[32][33];
    int c0 = blockIdx.x * 32, r0 = blockIdx.y * 32;
    long base = (long)blockIdx.z * R * C;
    int i = threadIdx.x >> 5, j = threadIdx.x & 31;
    #pragma unroll
    for (int p = 0; p < 4; p++) {
        int rr = i + p * 8;
        tile[rr][j] = src[base + (long)(r0 + rr) * C + c0 + j];
    }
    __syncthreads();
    #pragma unroll
    for (int p = 0; p < 4; p++) {
        int rr = i + p * 8;
        dst[base + (long)(c0 + rr) * R + r0 + j] = f2bf(tile[j][rr]);
    }
}

__global__ __launch_bounds__(256) void k_rope_tab(const float* __restrict__ freqs,
                                                  float* __restrict__ tc,
                                                  float* __restrict__ ts) {
    int idx = blockIdx.x * 256 + threadIdx.x;           // < 196*512
    int t = idx >> 9, n = idx & 511;
    float ph = (float)t * freqs[n];
    ph = (ph - floorf(ph)) * TWO_PI;
    tc[idx] = cosf(ph);
    ts[idx] = sinf(ph);
}

// ---------------------------------------------------------------------------
// GEMM kernels (256x256 8-phase core)
// ---------------------------------------------------------------------------
// tokens = patches @ convw^T + bias + pos_embed -> h   (M=12544,K=768,N=768)
__global__ __launch_bounds__(512, 2) void k_gemm_tokens(const u16* __restrict__ ap,
                                                        const u16* __restrict__ bw,
                                                        const float* __restrict__ cb,
                                                        const float* __restrict__ pe,
                                                        float* __restrict__ hout) {
    GEMM256_PROLOGUE
    int row0 = blockIdx.x * 256, col0 = blockIdx.y * 256;
    gemm256p(ap + (long)row0 * 768, 768, bw + (long)col0 * 768, 768, 12,
             acc, lds_a, lds_b);
    EPI256_VARS
    #pragma unroll
    for (int m = 0; m < 8; m++)
        #pragma unroll
        for (int n = 0; n < 4; n++)
            #pragma unroll
            for (int i = 0; i < 4; i++) {
                int row = row0 + ewr + 16 * m + i;
                int col = col0 + ewc + 16 * n;
                int t = row % 196;
                hout[(long)row * 768 + col] = acc[m][n][i] + cb[col] + pe[t * 768 + col];
            }
}

// chunk: x_sparse = relu(hn@enc); qr = rope(x_sparse)  (M=3136 masked, N=6144)
// xs/qr written HEAD-MAJOR: [(head*16+bL)*196 + t][512]
__global__ __launch_bounds__(512, 2) void k_gemm_xs(const u16* __restrict__ hnb,
                                                    const u16* __restrict__ enct,
                                                    const float* __restrict__ tc,
                                                    const float* __restrict__ tsn,
                                                    u16* __restrict__ xs,
                                                    u16* __restrict__ qr) {
    GEMM256_PROLOGUE
    // XCD swizzle: grid (13,24) -> 312 wgs = 8*39 (bijective)
    int p = blockIdx.x + 13 * blockIdx.y;
    int w = (p & 7) * 39 + (p >> 3);
    int row0 = (w % 13) * 256, col0 = (w / 13) * 256;
    int head = col0 >> 9;
    gemm256p(hnb + (long)row0 * 768, 768,
             enct + ((long)head * 512 + (col0 & 511)) * 768, 768, 12,
             acc, lds_a, lds_b);
    EPI256_VARS
    #pragma unroll
    for (int m = 0; m < 8; m++)
        #pragma unroll
        for (int n = 0; n < 4; n++)
            #pragma unroll
            for (int i = 0; i < 4; i++) {
                int row = row0 + ewr + 16 * m + i;   // chunk-local bL*196+t
                int col = col0 + ewc + 16 * n;
                float v = fmaxf(acc[m][n][i], 0.f);
                float pp = __shfl_xor(v, 1);         // all lanes participate
                if (row < MC) {
                    int bL = row / 196, t = row - bL * 196;
                    int nn = col & 511;
                    float cs = tc[t * 512 + nn], sn = tsn[t * 512 + nn];
                    float rot = (nn & 1) ? pp : -pp;
                    float qv = v * cs + rot * sn;
                    long o = ((long)(head * 16 + bL) * 196 + t) * 512 + nn;
                    xs[o] = f2bf(v);
                    qr[o] = f2bf(qv);
                }
            }
}

// ---------------------------------------------------------------------------
// Fused attention: one block per (row-tile 128, bh'=h*16+bL). Scores in regs
// (128x256 via acc0+acc1), in-register softmax, P bf16 in LDS [128][232]
// (cols 0..223 only; 196..223 zero pad), PV = P x hnT over 6 col-tiles.
// Uses the BK=32 core (unchanged).
// ---------------------------------------------------------------------------
__global__ __launch_bounds__(256) void k_attn(const u16* __restrict__ qr,
                                              const u16* __restrict__ hnT,
                                              u16* __restrict__ ykv) {
    __shared__ alignas(16) u16 lds_a[128 * 32];
    __shared__ alignas(16) u16 lds_b[128 * 32];
    __shared__ alignas(16) u16 Pl[128 * 232];
    __shared__ float part[2][128][2];    // [max|sum][row][wave-col-half]
    const int tid = threadIdx.x, lane = tid & 63, wave = tid >> 6;
    const int wr = (wave >> 1) * 64, wc = (wave & 1) * 64;
    const int lr = lane & 15, lk = (lane >> 4) * 8;
    const int row0 = blockIdx.x * 128, bh = blockIdx.y;  // bh = h*16+bL
    const int bL = bh & 15;
    const u16* qbase = qr + (long)bh * 196 * 512;

    f32x4 acc0[4][4], acc1[4][4];
    #pragma unroll
    for (int m = 0; m < 4; m++)
        #pragma unroll
        for (int n = 0; n < 4; n++) {
            acc0[m][n] = (f32x4){0.f, 0.f, 0.f, 0.f};
            acc1[m][n] = (f32x4){0.f, 0.f, 0.f, 0.f};
        }
    // scores: S[row, col] = Q[row0+row] . Q[col], two 128-col tiles (K=512)
    gemm_core(qbase + (long)row0 * 512, 512, qbase, 512, 16, acc0, lds_a, lds_b);
    gemm_core(qbase + (long)row0 * 512, 512, qbase + 128 * 512, 512, 16, acc1, lds_a, lds_b);

    // ---- softmax over cols (valid < 196), scale applied inside exp ----
    const int rb = wr + (lane >> 4) * 4;
    // pass 1: per-wave-half row maxes
    #pragma unroll
    for (int m = 0; m < 4; m++)
        #pragma unroll
        for (int i = 0; i < 4; i++) {
            float mx = -1e30f;
            #pragma unroll
            for (int n = 0; n < 4; n++) {
                int c0 = wc + 16 * n + lr;
                if (c0 < 196) mx = fmaxf(mx, acc0[m][n][i]);
                if (c0 + 128 < 196) mx = fmaxf(mx, acc1[m][n][i]);
            }
            #pragma unroll
            for (int o = 1; o < 16; o <<= 1) mx = fmaxf(mx, __shfl_xor(mx, o));
            if (lr == 0) part[0][rb + 16 * m + i][wave & 1] = mx;
        }
    __syncthreads();
    // pass 2: e = exp((S - rowmax)*scale), overwrite acc, partial sums
    #pragma unroll
    for (int m = 0; m < 4; m++)
        #pragma unroll
        for (int i = 0; i < 4; i++) {
            int row = rb + 16 * m + i;
            float rmx = fmaxf(part[0][row][0], part[0][row][1]);
            float s = 0.f;
            #pragma unroll
            for (int n = 0; n < 4; n++) {
                int c0 = wc + 16 * n + lr;
                float e0 = (c0 < 196) ? __expf((acc0[m][n][i] - rmx) * SM_SCALE) : 0.f;
                float e1 = (c0 + 128 < 196) ? __expf((acc1[m][n][i] - rmx) * SM_SCALE) : 0.f;
                acc0[m][n][i] = e0; acc1[m][n][i] = e1;
                s += e0 + e1;
            }
            #pragma unroll
            for (int o = 1; o < 16; o <<= 1) s += __shfl_xor(s, o);
            if (lr == 0) part[1][row][wave & 1] = s;
        }
    __syncthreads();
    // pass 3: P = e / rowsum -> LDS bf16, cols < 224 only (stride 232)
    #pragma unroll
    for (int m = 0; m < 4; m++)
        #pragma unroll
        for (int i = 0; i < 4; i++) {
            int row = rb + 16 * m + i;
            float inv = 1.f / (part[1][row][0] + part[1][row][1]);
            #pragma unroll
            for (int n = 0; n < 4; n++) {
                int c0 = wc + 16 * n + lr;
                Pl[row * 232 + c0] = f2bf(acc0[m][n][i] * inv);
                if (c0 + 128 < 224)
                    Pl[row * 232 + c0 + 128] = f2bf(acc1[m][n][i] * inv);
            }
        }
    // ---- PV: O[row, d] = sum_s P[row,s] * hnT[d][s], 6 col-tiles, K=224 ----
    const int srow = tid >> 2, scol = (tid & 3) * 8;
    for (int cd = 0; cd < 6; ++cd) {
        const u16* Bt = hnT + ((long)bL * 768 + cd * 128) * 224;
        f32x4 acc[4][4];
        #pragma unroll
        for (int m = 0; m < 4; m++)
            #pragma unroll
            for (int n = 0; n < 4; n++) acc[m][n] = (f32x4){0.f, 0.f, 0.f, 0.f};
        for (int k0 = 0; k0 < 7; ++k0) {
            __syncthreads();
            gload16(Bt + (long)srow * 224 + k0 * 32 + scol, lds_b + tid * 8);
            gload16(Bt + (long)(srow + 64) * 224 + k0 * 32 + scol, lds_b + 2048 + tid * 8);
            __syncthreads();
            bf16x8 af[4], bfr[4];
            #pragma unroll
            for (int m = 0; m < 4; m++)
                af[m] = *(const bf16x8*)&Pl[(wr + 16 * m + lr) * 232 + k0 * 32 + lk];
            #pragma unroll
            for (int n = 0; n < 4; n++)
                bfr[n] = *(const bf16x8*)&lds_b[(wc + 16 * n + lr) * 32 + lk];
            #pragma unroll
            for (int m = 0; m < 4; m++)
                #pragma unroll
                for (int n = 0; n < 4; n++)
                    acc[m][n] = __builtin_amdgcn_mfma_f32_16x16x32_bf16(af[m], bfr[n], acc[m][n], 0, 0, 0);
        }
        EPI_VARS
        #pragma unroll
        for (int m = 0; m < 4; m++)
            #pragma unroll
            for (int n = 0; n < 4; n++)
                #pragma unroll
                for (int i = 0; i < 4; i++) {
                    int trow = row0 + ewr + 16 * m + i;
                    if (trow < 196)
                        ykv[((long)bh * 196 + trow) * 768 + cd * 128 + ewc + 16 * n] =
                            f2bf(acc[m][n][i]);
                }
    }
}

// in-place LN over D of each row of yKV (order-agnostic)
__global__ __launch_bounds__(256) void k_ln_ykv(u16* __restrict__ ykv) {
    __shared__ float sm[4];
    int r = blockIdx.x, tid = threadIdx.x;
    u16* p = ykv + (long)r * 768;
    float x0 = bf2f(p[tid]), x1 = bf2f(p[tid + 256]), x2 = bf2f(p[tid + 512]);
    float mean = block_reduce_sum(x0 + x1 + x2, sm) * (1.f / 768.f);
    float d0 = x0 - mean, d1 = x1 - mean, d2 = x2 - mean;
    float var = block_reduce_sum(d0 * d0 + d1 * d1 + d2 * d2, sm) * (1.f / 768.f);
    float rs = rsqrtf(var + LN_EPS);
    p[tid] = f2bf(d0 * rs); p[tid + 256] = f2bf(d1 * rs); p[tid + 512] = f2bf(d2 * rs);
}

// y_sparse = relu(yKV @ encv); z = x_sparse*y_sparse, head-major flatten.
// HEAD-MAJOR: per h, A = ykv[h*3136 ...] contiguous M=3136; grid (13,2,12).
__global__ __launch_bounds__(512, 2) void k_gemm_ys(const u16* __restrict__ ykv,
                                                    const u16* __restrict__ encvt,
                                                    const u16* __restrict__ xs,
                                                    u16* __restrict__ z) {
    GEMM256_PROLOGUE
    // XCD swizzle: 312 wgs = 8*39 (bijective)
    int p = blockIdx.x + 13 * (blockIdx.y + 2 * blockIdx.z);
    int w = (p & 7) * 39 + (p >> 3);
    int rt = w % 13, rem = w / 13;
    int ct = rem & 1, h = rem >> 1;
    int row0 = rt * 256, col0 = ct * 256;
    gemm256p(ykv + ((long)h * MC + row0) * 768, 768,
             encvt + ((long)h * 512 + col0) * 768, 768, 12,
             acc, lds_a, lds_b);
    EPI256_VARS
    #pragma unroll
    for (int m = 0; m < 8; m++)
        #pragma unroll
        for (int n = 0; n < 4; n++)
            #pragma unroll
            for (int i = 0; i < 4; i++) {
                int row = row0 + ewr + 16 * m + i;   // bL*196+t
                int col = col0 + ewc + 16 * n;       // n in 0..511
                if (row < MC) {
                    float v = fmaxf(acc[m][n][i], 0.f) *
                              bf2f(xs[((long)h * MC + row) * 512 + col]);
                    z[(long)row * 6144 + h * 512 + col] = f2bf(v);
                }
            }
}

// yMLP_raw partial s = z[:, s*1024:(s+1)*1024] @ dec[s...]  (split-K6)
__global__ __launch_bounds__(512, 2) void k_gemm_mlp(const u16* __restrict__ z,
                                                     const u16* __restrict__ dect,
                                                     float* __restrict__ rawK) {
    GEMM256_PROLOGUE
    int row0 = blockIdx.x * 256, col0 = blockIdx.y * 256, s = blockIdx.z;
    gemm256p(z + (long)row0 * 6144 + s * 1024, 6144,
             dect + (long)col0 * 6144 + s * 1024, 6144, 16,
             acc, lds_a, lds_b);
    EPI256_VARS
    float* raw = rawK + (long)s * MC * 768;
    #pragma unroll
    for (int m = 0; m < 8; m++)
        #pragma unroll
        for (int n = 0; n < 4; n++)
            #pragma unroll
            for (int i = 0; i < 4; i++) {
                int row = row0 + ewr + 16 * m + i;
                int col = col0 + ewc + 16 * n;
                if (row < MC)
                    raw[(long)row * 768 + col] = acc[m][n][i];
            }
}

// ---------------------------------------------------------------------------
// per-row LN kernels
// ---------------------------------------------------------------------------
// hn = LN(h) -> hn bf16 (row-major only; hnT built by k_hnT)
__global__ __launch_bounds__(256) void k_ln1(const float* __restrict__ h,
                                             u16* __restrict__ hnb) {
    __shared__ float sm[4];
    int r = blockIdx.x, tid = threadIdx.x;
    const float* p = h + (long)r * 768;
    float x0 = p[tid], x1 = p[tid + 256], x2 = p[tid + 512];
    float mean = block_reduce_sum(x0 + x1 + x2, sm) * (1.f / 768.f);
    float d0 = x0 - mean, d1 = x1 - mean, d2 = x2 - mean;
    float var = block_reduce_sum(d0 * d0 + d1 * d1 + d2 * d2, sm) * (1.f / 768.f);
    float rs = rsqrtf(var + LN_EPS);
    long ro = (long)r * 768;
    hnb[ro + tid] = f2bf(d0 * rs);
    hnb[ro + tid + 256] = f2bf(d1 * rs);
    hnb[ro + tid + 512] = f2bf(d2 * rs);
}

// hnT[b][d][tpad224] = hnb[b*196+t][d], t-pad zero-filled. 32x32 LDS tiles.
__global__ __launch_bounds__(256) void k_hnT(const u16* __restrict__ hnb,
                                             u16* __restrict__ hnT) {
    __shared__ u16 tile[32][33];
    int t0 = blockIdx.x * 32, d0 = blockIdx.y * 32, b = blockIdx.z;
    int i = threadIdx.x >> 5, j = threadIdx.x & 31;
    #pragma unroll
    for (int p = 0; p < 4; p++) {
        int t = t0 + i + p * 8;
        tile[i + p * 8][j] = (t < 196) ? hnb[((long)b * 196 + t) * 768 + d0 + j] : (u16)0;
    }
    __syncthreads();
    #pragma unroll
    for (int p = 0; p < 4; p++) {
        int dd = i + p * 8;
        hnT[((long)b * 768 + d0 + dd) * 224 + t0 + j] = tile[j][dd];
    }
}

// h = LN(hn + LN(sum of 6 split-K partials))
__global__ __launch_bounds__(256) void k_final_h(const float* __restrict__ rawK,
                                                 const u16* __restrict__ hnb,
                                                 float* __restrict__ h) {
    __shared__ float sm[4];
    const long PS = (long)MC * 768;
    int r = blockIdx.x, tid = threadIdx.x;
    const u16* hp = hnb + (long)r * 768;
    float y0 = 0.f, y1 = 0.f, y2 = 0.f;
    #pragma unroll
    for (int s2 = 0; s2 < 6; ++s2) {
        const float* rp = rawK + s2 * PS + (long)r * 768;
        y0 += rp[tid]; y1 += rp[tid + 256]; y2 += rp[tid + 512];
    }
    float mean = block_reduce_sum(y0 + y1 + y2, sm) * (1.f / 768.f);
    float d0 = y0 - mean, d1 = y1 - mean, d2 = y2 - mean;
    float var = block_reduce_sum(d0 * d0 + d1 * d1 + d2 * d2, sm) * (1.f / 768.f);
    float rs = rsqrtf(var + LN_EPS);
    float s0 = bf2f(hp[tid]) + d0 * rs;
    float s1 = bf2f(hp[tid + 256]) + d1 * rs;
    float s2v = bf2f(hp[tid + 512]) + d2 * rs;
    mean = block_reduce_sum(s0 + s1 + s2v, sm) * (1.f / 768.f);
    d0 = s0 - mean; d1 = s1 - mean; d2 = s2v - mean;
    var = block_reduce_sum(d0 * d0 + d1 * d1 + d2 * d2, sm) * (1.f / 768.f);
    rs = rsqrtf(var + LN_EPS);
    long ro = (long)r * 768;
    h[ro + tid] = d0 * rs; h[ro + tid + 256] = d1 * rs; h[ro + tid + 512] = d2 * rs;
}

// pool stage 1: partial sums over 14-row groups -> part[b][g][768]
__global__ __launch_bounds__(256) void k_pool1(const float* __restrict__ h,
                                               float* __restrict__ part) {
    int g = blockIdx.x, b = blockIdx.y, tid = threadIdx.x;
    const float* base = h + ((long)b * 196 + g * 14) * 768;
    float a0 = 0.f, a1 = 0.f, a2 = 0.f;
    for (int t = 0; t < 14; t++) {
        const float* p = base + (long)t * 768;
        a0 += p[tid]; a1 += p[tid + 256]; a2 += p[tid + 512];
    }
    float* pp = part + ((long)b * 14 + g) * 768;
    pp[tid] = a0; pp[tid + 256] = a1; pp[tid + 512] = a2;
}

// pool stage 2: pooled = LN(sum(part)/196)
__global__ __launch_bounds__(256) void k_pool2(const float* __restrict__ part,
                                               float* __restrict__ pooled) {
    __shared__ float sm[4];
    int b = blockIdx.x, tid = threadIdx.x;
    const float* pp = part + (long)b * 14 * 768;
    float a0 = 0.f, a1 = 0.f, a2 = 0.f;
    for (int g = 0; g < 14; g++) {
        a0 += pp[g * 768 + tid]; a1 += pp[g * 768 + tid + 256]; a2 += pp[g * 768 + tid + 512];
    }
    a0 *= (1.f / 196.f); a1 *= (1.f / 196.f); a2 *= (1.f / 196.f);
    float mean = block_reduce_sum(a0 + a1 + a2, sm) * (1.f / 768.f);
    float d0 = a0 - mean, d1 = a1 - mean, d2 = a2 - mean;
    float var = block_reduce_sum(d0 * d0 + d1 * d1 + d2 * d2, sm) * (1.f / 768.f);
    float rs = rsqrtf(var + LN_EPS);
    pooled[(long)b * 768 + tid] = d0 * rs;
    pooled[(long)b * 768 + tid + 256] = d1 * rs;
    pooled[(long)b * 768 + tid + 512] = d2 * rs;
}

// out = pooled @ head_w^T + head_b.  grid (250, 64): wave w -> col 4*bx+w.
__global__ __launch_bounds__(256) void k_head(const float* __restrict__ pooled,
                                              const float* __restrict__ hw,
                                              const float* __restrict__ hb,
                                              float* __restrict__ out) {
    __shared__ float pr[768];
    int b = blockIdx.y, tid = threadIdx.x;
    pr[tid] = pooled[(long)b * 768 + tid];
    pr[tid + 256] = pooled[(long)b * 768 + tid + 256];
    pr[tid + 512] = pooled[(long)b * 768 + tid + 512];
    __syncthreads();
    int c = blockIdx.x * 4 + (tid >> 6);
    int lane = tid & 63;
    const float* wrow = hw + (long)c * 768;
    float acc = 0.f;
    #pragma unroll
    for (int k = 0; k < 768; k += 64) acc += pr[k + lane] * wrow[k + lane];
    #pragma unroll
    for (int o = 32; o; o >>= 1) acc += __shfl_xor(acc, o);
    if (lane == 0) out[(long)b * 1000 + c] = acc + hb[c];
}

// ---------------------------------------------------------------------------
extern "C" void kernel_launch(void* const* d_in, const int* in_sizes, int n_in,
                              void* d_out, int out_size, void* d_ws, size_t ws_size,
                              hipStream_t stream) {
    const float* x     = (const float*)d_in[0];
    const float* convw = (const float*)d_in[1];
    const float* convb = (const float*)d_in[2];
    const float* pe    = (const float*)d_in[3];
    const float* enc   = (const float*)d_in[4];
    const float* encv  = (const float*)d_in[5];
    const float* dec   = (const float*)d_in[6];
    const float* freqs = (const float*)d_in[7];
    const float* hw    = (const float*)d_in[8];
    const float* hbias = (const float*)d_in[9];
    float* out = (float*)d_out;

    char* W = (char*)d_ws;
    size_t off = 0;
    auto ALLOC = [&](size_t bytes) {
        size_t o = off;
        off += (bytes + 255) & ~(size_t)255;
        return o;
    };
    // persistent
    float* bh    = (float*)(W + ALLOC(38535168));            // h f32 (12544x768)
    u16*   bhnb  = (u16*)  (W + ALLOC(19267584 + 524288));   // hn bf16 (+256-tile edge slack)
    u16*   bhnT  = (u16*)  (W + ALLOC(22020096));            // hn^T bf16 (64,768,224)
    u16*   benc  = (u16*)  (W + ALLOC(9437184));             // enc^T  (12,512,768)
    u16*   bencv = (u16*)  (W + ALLOC(9437184));             // encv^T
    u16*   bdec  = (u16*)  (W + ALLOC(9437184));             // dec^T  (768,6144)
    float* btc   = (float*)(W + ALLOC(401408));              // cos (196,512)
    float* bts   = (float*)(W + ALLOC(401408));              // sin
    float* bpool = (float*)(W + ALLOC(196608));              // pooled (64,768)
    float* bpart = (float*)(W + ALLOC(2752512));             // pool partials (64,14,768)
    // chunk regions (+slack for masked edge-tile overreads: 192 rows x lda)
    char*  R1    = (char*) (W + ALLOC(38535168 + 4194304));  // qr / z (z edge: 192*12288B)
    char*  R2    = (char*) (W + ALLOC(57802752 + 524288));   // ykv / rawK (+setup patches)
    char*  R3    = (char*) (W + ALLOC(38535168 + 524288));   // xs (+setup conv_w)
    (void)ws_size; (void)in_sizes; (void)n_in; (void)out_size;
    // total ~252 MiB

    u16*   bap  = (u16*)R2;    // setup: packed patches (18.4M)
    u16*   bcw  = (u16*)R3;    // setup: conv_w bf16 (1.2M)
    u16*   qr   = (u16*)R1;    // per-chunk head-major (192hb,196,512)
    u16*   z    = (u16*)R1;    // (3136,6144)
    u16*   ykv  = (u16*)R2;    // head-major (192hb,196,768)
    float* rawK = (float*)R2;  // yMLP split-K partials 6x(3136,768) f32 = 57.8MB
    u16*   xs   = (u16*)R3;    // head-major (192hb,196,512)

    // ---- setup ----
    k_pack_patches<<<37632, 256, 0, stream>>>(x, bap);
    k_cast<<<2304, 256, 0, stream>>>(convw, bcw, 768 * 768);
    k_gemm_tokens<<<dim3(49, 3), 512, 0, stream>>>(bap, bcw, convb, pe, bh);
    k_transpose_cast<<<dim3(16, 24, 12), 256, 0, stream>>>(enc, benc, 768, 512);
    k_transpose_cast<<<dim3(16, 24, 12), 256, 0, stream>>>(encv, bencv, 768, 512);
    k_transpose_cast<<<dim3(24, 192, 1), 256, 0, stream>>>(dec, bdec, 6144, 768);
    k_rope_tab<<<392, 256, 0, stream>>>(freqs, btc, bts);

    // ---- 6 shared-weight layers, 4 chunks of 16 images each ----
    for (int L = 0; L < 6; ++L) {
        k_ln1<<<12544, 256, 0, stream>>>(bh, bhnb);
        k_hnT<<<dim3(7, 24, 64), 256, 0, stream>>>(bhnb, bhnT);
        for (int c = 0; c < 4; ++c) {
            long r0 = (long)c * MC;                    // chunk row offset
            k_gemm_xs<<<dim3(13, 24), 512, 0, stream>>>(
                bhnb + r0 * 768, benc, btc, bts, xs, qr);
            k_attn<<<dim3(2, 192), 256, 0, stream>>>(
                qr, bhnT + (long)c * 16 * 768 * 224, ykv);
            k_ln_ykv<<<37632, 256, 0, stream>>>(ykv);
            k_gemm_ys<<<dim3(13, 2, 12), 512, 0, stream>>>(ykv, bencv, xs, z);
            k_gemm_mlp<<<dim3(13, 3, 6), 512, 0, stream>>>(z, bdec, rawK);
            k_final_h<<<MC, 256, 0, stream>>>(rawK, bhnb + r0 * 768, bh + r0 * 768);
        }
    }

    // ---- head ----
    k_pool1<<<dim3(14, 64), 256, 0, stream>>>(bh, bpart);
    k_pool2<<<64, 256, 0, stream>>>(bpart, bpool);
    k_head<<<dim3(250, 64), 256, 0, stream>>>(bpool, hw, hbias, out);
}

// Round 3
// 8636.178 us; speedup vs baseline: 1.0292x; 1.0010x over previous
//
#include <hip/hip_runtime.h>
#include <hip/hip_bf16.h>

// ============================================================================
// VisionBDHv2 forward, MI355X (gfx950). Round 10.
// R7: 7775us (128x128 2-barrier core; ~latency bound, 12% Mfma).
// R8: 8888us (256x256 2-phase dbuf: drain-on-critical-path, no TLP).
// R9: 8644us (256x256 8-phase, counted vmcnt): FLAT vs R8 - 2675 cyc/phase vs
//     620 MFMA-bound. Diagnosis: plain-C++ ds_reads of a buffer with
//     outstanding global_load_lds get compiler-inserted conservative vmcnt
//     waits (LDS-DMA alias hazard) -> every phase drains the just-issued
//     stages = full HBM latency per phase. R8==R9 confirms waits execute
//     regardless of my asm vmcnt placement.
// R10: make LDS reads invisible to the waitcnt legalizer:
//   - inline-asm ds_read_b128, loop-invariant per-lane base addrs (swizzle
//     folded in), compile-time offset: immediates
//   - explicit s_waitcnt lgkmcnt(0) + sched_barrier(0) before MFMA (rule 18)
//   - everything else byte-identical to R9 (calendar, grids, epilogues)
// attn keeps the old BK=32 core (isolation).
// ============================================================================

typedef short bf16x8 __attribute__((ext_vector_type(8)));
typedef float f32x4 __attribute__((ext_vector_type(4)));
typedef unsigned short u16;

#define LN_EPS 1e-5f
#define SM_SCALE 0.044194173824159216f  /* 1/sqrt(512) */
#define TWO_PI 6.283185307179586f
#define MC 3136                          /* rows per chunk = 16*196 */

typedef __attribute__((address_space(3))) unsigned char* as3p;
typedef const __attribute__((address_space(1))) unsigned char* as1p;

__device__ __forceinline__ void gload16(const u16* g, u16* l) {
    __builtin_amdgcn_global_load_lds((as1p)(const void*)g, (as3p)(void*)l, 16, 0, 0);
}

__device__ __forceinline__ unsigned ldsoff(const u16* p) {
    return (unsigned)(unsigned long long)(as3p)(void*)(u16*)p;
}

// opaque ds_read_b128: no compiler-tracked memory dep -> no legalizer waits
#define DSR(dst, addr, imm)                                                  \
    asm volatile("ds_read_b128 %0, %1 offset:%c2"                            \
                 : "=v"(dst) : "v"(addr), "i"(imm));

__device__ __forceinline__ u16 f2bf(float f) {
    __hip_bfloat16 h = __float2bfloat16(f);
    return *reinterpret_cast<u16*>(&h);
}
__device__ __forceinline__ float bf2f(u16 u) {
    return __uint_as_float(((unsigned)u) << 16);
}

// ---------------------------------------------------------------------------
// block reductions (256 threads, 4 waves)
// ---------------------------------------------------------------------------
__device__ __forceinline__ float block_reduce_sum(float v, float* sm) {
    #pragma unroll
    for (int o = 32; o; o >>= 1) v += __shfl_xor(v, o);
    if ((threadIdx.x & 63) == 0) sm[threadIdx.x >> 6] = v;
    __syncthreads();
    float r = sm[0] + sm[1] + sm[2] + sm[3];
    __syncthreads();
    return r;
}

// ---------------------------------------------------------------------------
// GEMM core v6: 256x256 tile, BK=64, 512 threads (8 waves, 2Mx4N), 8-phase
// pipelined schedule, counted vmcnt, ASM ds_reads. LDS: 2 parities x
// [256][64] u16 per operand (128 KiB). Tile t -> parity t&1.
// Stage calendar (iteration i, tiles T=2i / U=T+1):
//   T.p0:A(T+1)h0  T.p1:A(T+1)h1  T.p2:B(T+2)h0  T.p3:B(T+2)h1 +vmcnt(4)
//   U.p0:A(T+2)h0  U.p1:A(T+2)h1  U.p2:B(T+3)h0  U.p3:B(T+3)h1 +vmcnt(4)
// (last iter: T stages only A(U); T.p3 waits vmcnt(0); U stages nothing.)
// Audit: every stage lands >=1 barrier after the last read of the region it
// overwrites; at each wait, all data needed for the next tile is drained.
// Swizzle: physical 16B slot s holds logical s^(row&7); global source col
// pre-swizzled (involution), linear LDS dest, asm read applies same XOR via
// per-lane base address. ds_read byte addr = base + (waveRow+lr)*128 +
// ((lg+4kk)^rx)*16  [loop-invariant reg]  + imm{PAR*32768 + rowblk*2048}.
// ---------------------------------------------------------------------------
__device__ __forceinline__ void gemm256p(const u16* __restrict__ A, int lda,
                                         const u16* __restrict__ Bt, int ldb,
                                         int ktiles /*even, >=4*/, f32x4 acc[8][4],
                                         u16* lds_a, u16* lds_b) {
    const int tid = threadIdx.x;          // 0..511
    const int lane = tid & 63;
    const int wave = tid >> 6;            // 0..7
    const int wr = (wave >> 2) * 128;     // wave row origin (2 M-waves)
    const int wc = (wave & 3) * 64;       // wave col origin (4 N-waves)
    const int lr = lane & 15;
    const int lg = lane >> 4;             // logical k-slot base (0..3)
    const int rx = lr & 7;
    const int srow = tid >> 3;            // staging row within 128-row slab
    const int gslot = (tid & 7) ^ (srow & 7);  // pre-swizzled global col slot
    const u16* gA = A + (long)srow * lda + gslot * 8;
    const u16* gB = Bt + (long)srow * ldb + gslot * 8;
    u16* lA = lds_a + tid * 8;            // linear dest: row srow, slot tid&7
    u16* lB = lds_b + tid * 8;
    // loop-invariant ds_read byte addresses (within-LDS, swizzle folded in)
    const unsigned s0 = (unsigned)((lg ^ rx) * 16);
    const unsigned s1 = (unsigned)(((lg + 4) ^ rx) * 16);
    const unsigned aR0 = ldsoff(lds_a) + (wr + lr) * 128 + s0;
    const unsigned aR1 = ldsoff(lds_a) + (wr + lr) * 128 + s1;
    const unsigned bR0 = ldsoff(lds_b) + (wc + lr) * 128 + s0;
    const unsigned bR1 = ldsoff(lds_b) + (wc + lr) * 128 + s1;

// stage one half-tile (128 rows x 64 cols) of tile t, half h: 2 gload_lds
#define STG(gbase, ld, lbase, t, h)                                          \
    {                                                                        \
        const u16* gp_ = (gbase) + (long)((h) * 128) * (ld) + (t) * 64;      \
        u16* lp_ = (lbase) + ((t) & 1) * 16384 + (h) * 8192;                 \
        gload16(gp_, lp_);                                                   \
        gload16(gp_ + (long)64 * (ld), lp_ + 4096);                          \
    }

// one phase: asm ds-reads, stage slot, barrier, lgkm(0)+pin, MFMA, tail, barrier
#define PHASE(PAR, PH, LOADB, STGSTMT, TAILSTMT)                             \
    {                                                                        \
        if (LOADB) {                                                         \
            _Pragma("unroll")                                                \
            for (int n = 0; n < 4; ++n) {                                    \
                DSR(bfr[0][n], bR0, (PAR) * 32768 + n * 2048)                \
                DSR(bfr[1][n], bR1, (PAR) * 32768 + n * 2048)                \
            }                                                                \
        }                                                                    \
        bf16x8 af[2][2];                                                     \
        _Pragma("unroll")                                                    \
        for (int j = 0; j < 2; ++j) {                                        \
            DSR(af[0][j], aR0, (PAR) * 32768 + (2 * (PH) + j) * 2048)        \
            DSR(af[1][j], aR1, (PAR) * 32768 + (2 * (PH) + j) * 2048)        \
        }                                                                    \
        STGSTMT;                                                             \
        __builtin_amdgcn_s_barrier();                                        \
        asm volatile("s_waitcnt lgkmcnt(0)" ::: "memory");                   \
        __builtin_amdgcn_sched_barrier(0);                                   \
        __builtin_amdgcn_s_setprio(1);                                       \
        _Pragma("unroll")                                                    \
        for (int kk = 0; kk < 2; ++kk)                                       \
            _Pragma("unroll")                                                \
            for (int j = 0; j < 2; ++j)                                      \
                _Pragma("unroll")                                            \
                for (int n = 0; n < 4; ++n)                                  \
                    acc[2 * (PH) + j][n] = __builtin_amdgcn_mfma_f32_16x16x32_bf16( \
                        af[kk][j], bfr[kk][n], acc[2 * (PH) + j][n], 0, 0, 0); \
        __builtin_amdgcn_s_setprio(0);                                       \
        TAILSTMT;                                                            \
        __builtin_amdgcn_s_barrier();                                        \
    }

    // prologue: B(0), A(0), B(1) staged; wait leaves B(1) (4 calls) in flight
    STG(gB, ldb, lB, 0, 0); STG(gB, ldb, lB, 0, 1);
    STG(gA, lda, lA, 0, 0); STG(gA, lda, lA, 0, 1);
    STG(gB, ldb, lB, 1, 0); STG(gB, ldb, lB, 1, 1);
    asm volatile("s_waitcnt vmcnt(4)" ::: "memory");
    __builtin_amdgcn_sched_barrier(0);
    __builtin_amdgcn_s_barrier();

    const int iters = ktiles >> 1;
    for (int i = 0; i < iters; ++i) {
        const int T = 2 * i;
        const bool last = (i == iters - 1);
        // ---------- tile T (parity 0): phases 1-4 ----------
        {
            bf16x8 bfr[2][4];
            PHASE(0, 0, true,  STG(gA, lda, lA, T + 1, 0), )
            PHASE(0, 1, false, STG(gA, lda, lA, T + 1, 1), )
            PHASE(0, 2, false, if (!last) STG(gB, ldb, lB, T + 2, 0), )
            PHASE(0, 3, false, if (!last) STG(gB, ldb, lB, T + 2, 1),
                  if (last) { asm volatile("s_waitcnt vmcnt(0)" ::: "memory"); }
                  else      { asm volatile("s_waitcnt vmcnt(4)" ::: "memory"); }
                  __builtin_amdgcn_sched_barrier(0);)
        }
        // ---------- tile T+1 (parity 1): phases 5-8 ----------
        {
            bf16x8 bfr[2][4];
            PHASE(1, 0, true,  if (!last) STG(gA, lda, lA, T + 2, 0), )
            PHASE(1, 1, false, if (!last) STG(gA, lda, lA, T + 2, 1), )
            PHASE(1, 2, false, if (!last) STG(gB, ldb, lB, T + 3, 0), )
            PHASE(1, 3, false, if (!last) STG(gB, ldb, lB, T + 3, 1),
                  if (!last) {
                      asm volatile("s_waitcnt vmcnt(4)" ::: "memory");
                      __builtin_amdgcn_sched_barrier(0);
                  })
        }
    }
#undef PHASE
#undef STG
}

#define GEMM256_PROLOGUE                                \
    __shared__ alignas(16) u16 lds_a[2 * 256 * 64];     \
    __shared__ alignas(16) u16 lds_b[2 * 256 * 64];     \
    f32x4 acc[8][4];                                    \
    _Pragma("unroll")                                   \
    for (int m = 0; m < 8; m++)                         \
        _Pragma("unroll")                               \
        for (int n = 0; n < 4; n++)                     \
            acc[m][n] = (f32x4){0.f, 0.f, 0.f, 0.f};

#define EPI256_VARS                                     \
    const int lane = threadIdx.x & 63;                  \
    const int wave = threadIdx.x >> 6;                  \
    const int ewr = (wave >> 2) * 128 + (lane >> 4) * 4;\
    const int ewc = (wave & 3) * 64 + (lane & 15);

// ---------------------------------------------------------------------------
// GEMM core v2 (BK=32, linear, 256 threads) — used by k_attn only.
// ---------------------------------------------------------------------------
__device__ __forceinline__ void gemm_core(const u16* __restrict__ A, int lda,
                                          const u16* __restrict__ Bt, int ldb,
                                          int ksteps, f32x4 acc[4][4],
                                          u16* lds_a, u16* lds_b) {
    const int tid = threadIdx.x;
    const int lane = tid & 63;
    const int wave = tid >> 6;
    const int wr = (wave >> 1) * 64;
    const int wc = (wave & 1) * 64;
    const int lr = lane & 15;
    const int lk = (lane >> 4) * 8;
    const int srow = tid >> 2;
    const int scol = (tid & 3) * 8;
    const u16* ga = A + (long)srow * lda + scol;
    const u16* gb = Bt + (long)srow * ldb + scol;
    const long ha = (long)64 * lda;
    const long hb = (long)64 * ldb;
    u16* la = lds_a + tid * 8;
    u16* lb = lds_b + tid * 8;
    for (int k0 = 0; k0 < ksteps; ++k0) {
        __syncthreads();
        gload16(ga, la);
        gload16(ga + ha, la + 2048);
        gload16(gb, lb);
        gload16(gb + hb, lb + 2048);
        ga += 32; gb += 32;
        __syncthreads();
        bf16x8 af[4], bfr[4];
        #pragma unroll
        for (int m = 0; m < 4; m++)
            af[m] = *(const bf16x8*)&lds_a[(wr + 16 * m + lr) * 32 + lk];
        #pragma unroll
        for (int n = 0; n < 4; n++)
            bfr[n] = *(const bf16x8*)&lds_b[(wc + 16 * n + lr) * 32 + lk];
        #pragma unroll
        for (int m = 0; m < 4; m++)
            #pragma unroll
            for (int n = 0; n < 4; n++)
                acc[m][n] = __builtin_amdgcn_mfma_f32_16x16x32_bf16(af[m], bfr[n], acc[m][n], 0, 0, 0);
    }
}

#define EPI_VARS                                        \
    const int lane = threadIdx.x & 63;                  \
    const int wave = threadIdx.x >> 6;                  \
    const int ewr = (wave >> 1) * 64 + (lane >> 4) * 4; \
    const int ewc = (wave & 1) * 64 + (lane & 15);

// ---------------------------------------------------------------------------
// setup kernels
// ---------------------------------------------------------------------------
__global__ __launch_bounds__(256) void k_pack_patches(const float* __restrict__ x,
                                                      u16* __restrict__ ap) {
    int idx = blockIdx.x * 256 + threadIdx.x;           // < 12544*768
    int r = idx / 768, k = idx - r * 768;
    int b = r / 196, t = r - b * 196;
    int hp = t / 14, wp = t - hp * 14;
    int c = k >> 8, rem = k & 255, p = rem >> 4, q = rem & 15;
    long src = ((long)(b * 3 + c) * 224 + hp * 16 + p) * 224 + wp * 16 + q;
    ap[idx] = f2bf(x[src]);
}

__global__ __launch_bounds__(256) void k_cast(const float* __restrict__ s,
                                              u16* __restrict__ d, int n) {
    int i = blockIdx.x * 256 + threadIdx.x;
    if (i < n) d[i] = f2bf(s[i]);
}

// src (batch, R, C) f32 -> dst (batch, C, R) bf16
__global__ __launch_bounds__(256) void k_transpose_cast(const float* __restrict__ src,
                                                        u16* __restrict__ dst,
                                                        int R, int C) {
    __shared__ float tile[32][33];
    int c0 = blockIdx.x * 32, r0 = blockIdx.y * 32;
    long base = (long)blockIdx.z * R * C;
    int i = threadIdx.x >> 5, j = threadIdx.x & 31;
    #pragma unroll
    for (int p = 0; p < 4; p++) {
        int rr = i + p * 8;
        tile[rr][j] = src[base + (long)(r0 + rr) * C + c0 + j];
    }
    __syncthreads();
    #pragma unroll
    for (int p = 0; p < 4; p++) {
        int rr = i + p * 8;
        dst[base + (long)(c0 + rr) * R + r0 + j] = f2bf(tile[j][rr]);
    }
}

__global__ __launch_bounds__(256) void k_rope_tab(const float* __restrict__ freqs,
                                                  float* __restrict__ tc,
                                                  float* __restrict__ ts) {
    int idx = blockIdx.x * 256 + threadIdx.x;           // < 196*512
    int t = idx >> 9, n = idx & 511;
    float ph = (float)t * freqs[n];
    ph = (ph - floorf(ph)) * TWO_PI;
    tc[idx] = cosf(ph);
    ts[idx] = sinf(ph);
}

// ---------------------------------------------------------------------------
// GEMM kernels (256x256 8-phase core)
// ---------------------------------------------------------------------------
// tokens = patches @ convw^T + bias + pos_embed -> h   (M=12544,K=768,N=768)
__global__ __launch_bounds__(512, 2) void k_gemm_tokens(const u16* __restrict__ ap,
                                                        const u16* __restrict__ bw,
                                                        const float* __restrict__ cb,
                                                        const float* __restrict__ pe,
                                                        float* __restrict__ hout) {
    GEMM256_PROLOGUE
    int row0 = blockIdx.x * 256, col0 = blockIdx.y * 256;
    gemm256p(ap + (long)row0 * 768, 768, bw + (long)col0 * 768, 768, 12,
             acc, lds_a, lds_b);
    EPI256_VARS
    #pragma unroll
    for (int m = 0; m < 8; m++)
        #pragma unroll
        for (int n = 0; n < 4; n++)
            #pragma unroll
            for (int i = 0; i < 4; i++) {
                int row = row0 + ewr + 16 * m + i;
                int col = col0 + ewc + 16 * n;
                int t = row % 196;
                hout[(long)row * 768 + col] = acc[m][n][i] + cb[col] + pe[t * 768 + col];
            }
}

// chunk: x_sparse = relu(hn@enc); qr = rope(x_sparse)  (M=3136 masked, N=6144)
// xs/qr written HEAD-MAJOR: [(head*16+bL)*196 + t][512]
__global__ __launch_bounds__(512, 2) void k_gemm_xs(const u16* __restrict__ hnb,
                                                    const u16* __restrict__ enct,
                                                    const float* __restrict__ tc,
                                                    const float* __restrict__ tsn,
                                                    u16* __restrict__ xs,
                                                    u16* __restrict__ qr) {
    GEMM256_PROLOGUE
    // XCD swizzle: grid (13,24) -> 312 wgs = 8*39 (bijective)
    int p = blockIdx.x + 13 * blockIdx.y;
    int w = (p & 7) * 39 + (p >> 3);
    int row0 = (w % 13) * 256, col0 = (w / 13) * 256;
    int head = col0 >> 9;
    gemm256p(hnb + (long)row0 * 768, 768,
             enct + ((long)head * 512 + (col0 & 511)) * 768, 768, 12,
             acc, lds_a, lds_b);
    EPI256_VARS
    #pragma unroll
    for (int m = 0; m < 8; m++)
        #pragma unroll
        for (int n = 0; n < 4; n++)
            #pragma unroll
            for (int i = 0; i < 4; i++) {
                int row = row0 + ewr + 16 * m + i;   // chunk-local bL*196+t
                int col = col0 + ewc + 16 * n;
                float v = fmaxf(acc[m][n][i], 0.f);
                float pp = __shfl_xor(v, 1);         // all lanes participate
                if (row < MC) {
                    int bL = row / 196, t = row - bL * 196;
                    int nn = col & 511;
                    float cs = tc[t * 512 + nn], sn = tsn[t * 512 + nn];
                    float rot = (nn & 1) ? pp : -pp;
                    float qv = v * cs + rot * sn;
                    long o = ((long)(head * 16 + bL) * 196 + t) * 512 + nn;
                    xs[o] = f2bf(v);
                    qr[o] = f2bf(qv);
                }
            }
}

// ---------------------------------------------------------------------------
// Fused attention: one block per (row-tile 128, bh'=h*16+bL). Scores in regs
// (128x256 via acc0+acc1), in-register softmax, P bf16 in LDS [128][232]
// (cols 0..223 only; 196..223 zero pad), PV = P x hnT over 6 col-tiles.
// Uses the BK=32 core (unchanged).
// ---------------------------------------------------------------------------
__global__ __launch_bounds__(256) void k_attn(const u16* __restrict__ qr,
                                              const u16* __restrict__ hnT,
                                              u16* __restrict__ ykv) {
    __shared__ alignas(16) u16 lds_a[128 * 32];
    __shared__ alignas(16) u16 lds_b[128 * 32];
    __shared__ alignas(16) u16 Pl[128 * 232];
    __shared__ float part[2][128][2];    // [max|sum][row][wave-col-half]
    const int tid = threadIdx.x, lane = tid & 63, wave = tid >> 6;
    const int wr = (wave >> 1) * 64, wc = (wave & 1) * 64;
    const int lr = lane & 15, lk = (lane >> 4) * 8;
    const int row0 = blockIdx.x * 128, bh = blockIdx.y;  // bh = h*16+bL
    const int bL = bh & 15;
    const u16* qbase = qr + (long)bh * 196 * 512;

    f32x4 acc0[4][4], acc1[4][4];
    #pragma unroll
    for (int m = 0; m < 4; m++)
        #pragma unroll
        for (int n = 0; n < 4; n++) {
            acc0[m][n] = (f32x4){0.f, 0.f, 0.f, 0.f};
            acc1[m][n] = (f32x4){0.f, 0.f, 0.f, 0.f};
        }
    // scores: S[row, col] = Q[row0+row] . Q[col], two 128-col tiles (K=512)
    gemm_core(qbase + (long)row0 * 512, 512, qbase, 512, 16, acc0, lds_a, lds_b);
    gemm_core(qbase + (long)row0 * 512, 512, qbase + 128 * 512, 512, 16, acc1, lds_a, lds_b);

    // ---- softmax over cols (valid < 196), scale applied inside exp ----
    const int rb = wr + (lane >> 4) * 4;
    // pass 1: per-wave-half row maxes
    #pragma unroll
    for (int m = 0; m < 4; m++)
        #pragma unroll
        for (int i = 0; i < 4; i++) {
            float mx = -1e30f;
            #pragma unroll
            for (int n = 0; n < 4; n++) {
                int c0 = wc + 16 * n + lr;
                if (c0 < 196) mx = fmaxf(mx, acc0[m][n][i]);
                if (c0 + 128 < 196) mx = fmaxf(mx, acc1[m][n][i]);
            }
            #pragma unroll
            for (int o = 1; o < 16; o <<= 1) mx = fmaxf(mx, __shfl_xor(mx, o));
            if (lr == 0) part[0][rb + 16 * m + i][wave & 1] = mx;
        }
    __syncthreads();
    // pass 2: e = exp((S - rowmax)*scale), overwrite acc, partial sums
    #pragma unroll
    for (int m = 0; m < 4; m++)
        #pragma unroll
        for (int i = 0; i < 4; i++) {
            int row = rb + 16 * m + i;
            float rmx = fmaxf(part[0][row][0], part[0][row][1]);
            float s = 0.f;
            #pragma unroll
            for (int n = 0; n < 4; n++) {
                int c0 = wc + 16 * n + lr;
                float e0 = (c0 < 196) ? __expf((acc0[m][n][i] - rmx) * SM_SCALE) : 0.f;
                float e1 = (c0 + 128 < 196) ? __expf((acc1[m][n][i] - rmx) * SM_SCALE) : 0.f;
                acc0[m][n][i] = e0; acc1[m][n][i] = e1;
                s += e0 + e1;
            }
            #pragma unroll
            for (int o = 1; o < 16; o <<= 1) s += __shfl_xor(s, o);
            if (lr == 0) part[1][row][wave & 1] = s;
        }
    __syncthreads();
    // pass 3: P = e / rowsum -> LDS bf16, cols < 224 only (stride 232)
    #pragma unroll
    for (int m = 0; m < 4; m++)
        #pragma unroll
        for (int i = 0; i < 4; i++) {
            int row = rb + 16 * m + i;
            float inv = 1.f / (part[1][row][0] + part[1][row][1]);
            #pragma unroll
            for (int n = 0; n < 4; n++) {
                int c0 = wc + 16 * n + lr;
                Pl[row * 232 + c0] = f2bf(acc0[m][n][i] * inv);
                if (c0 + 128 < 224)
                    Pl[row * 232 + c0 + 128] = f2bf(acc1[m][n][i] * inv);
            }
        }
    // ---- PV: O[row, d] = sum_s P[row,s] * hnT[d][s], 6 col-tiles, K=224 ----
    const int srow = tid >> 2, scol = (tid & 3) * 8;
    for (int cd = 0; cd < 6; ++cd) {
        const u16* Bt = hnT + ((long)bL * 768 + cd * 128) * 224;
        f32x4 acc[4][4];
        #pragma unroll
        for (int m = 0; m < 4; m++)
            #pragma unroll
            for (int n = 0; n < 4; n++) acc[m][n] = (f32x4){0.f, 0.f, 0.f, 0.f};
        for (int k0 = 0; k0 < 7; ++k0) {
            __syncthreads();
            gload16(Bt + (long)srow * 224 + k0 * 32 + scol, lds_b + tid * 8);
            gload16(Bt + (long)(srow + 64) * 224 + k0 * 32 + scol, lds_b + 2048 + tid * 8);
            __syncthreads();
            bf16x8 af[4], bfr[4];
            #pragma unroll
            for (int m = 0; m < 4; m++)
                af[m] = *(const bf16x8*)&Pl[(wr + 16 * m + lr) * 232 + k0 * 32 + lk];
            #pragma unroll
            for (int n = 0; n < 4; n++)
                bfr[n] = *(const bf16x8*)&lds_b[(wc + 16 * n + lr) * 32 + lk];
            #pragma unroll
            for (int m = 0; m < 4; m++)
                #pragma unroll
                for (int n = 0; n < 4; n++)
                    acc[m][n] = __builtin_amdgcn_mfma_f32_16x16x32_bf16(af[m], bfr[n], acc[m][n], 0, 0, 0);
        }
        EPI_VARS
        #pragma unroll
        for (int m = 0; m < 4; m++)
            #pragma unroll
            for (int n = 0; n < 4; n++)
                #pragma unroll
                for (int i = 0; i < 4; i++) {
                    int trow = row0 + ewr + 16 * m + i;
                    if (trow < 196)
                        ykv[((long)bh * 196 + trow) * 768 + cd * 128 + ewc + 16 * n] =
                            f2bf(acc[m][n][i]);
                }
    }
}

// in-place LN over D of each row of yKV (order-agnostic)
__global__ __launch_bounds__(256) void k_ln_ykv(u16* __restrict__ ykv) {
    __shared__ float sm[4];
    int r = blockIdx.x, tid = threadIdx.x;
    u16* p = ykv + (long)r * 768;
    float x0 = bf2f(p[tid]), x1 = bf2f(p[tid + 256]), x2 = bf2f(p[tid + 512]);
    float mean = block_reduce_sum(x0 + x1 + x2, sm) * (1.f / 768.f);
    float d0 = x0 - mean, d1 = x1 - mean, d2 = x2 - mean;
    float var = block_reduce_sum(d0 * d0 + d1 * d1 + d2 * d2, sm) * (1.f / 768.f);
    float rs = rsqrtf(var + LN_EPS);
    p[tid] = f2bf(d0 * rs); p[tid + 256] = f2bf(d1 * rs); p[tid + 512] = f2bf(d2 * rs);
}

// y_sparse = relu(yKV @ encv); z = x_sparse*y_sparse, head-major flatten.
// HEAD-MAJOR: per h, A = ykv[h*3136 ...] contiguous M=3136; grid (13,2,12).
__global__ __launch_bounds__(512, 2) void k_gemm_ys(const u16* __restrict__ ykv,
                                                    const u16* __restrict__ encvt,
                                                    const u16* __restrict__ xs,
                                                    u16* __restrict__ z) {
    GEMM256_PROLOGUE
    // XCD swizzle: 312 wgs = 8*39 (bijective)
    int p = blockIdx.x + 13 * (blockIdx.y + 2 * blockIdx.z);
    int w = (p & 7) * 39 + (p >> 3);
    int rt = w % 13, rem = w / 13;
    int ct = rem & 1, h = rem >> 1;
    int row0 = rt * 256, col0 = ct * 256;
    gemm256p(ykv + ((long)h * MC + row0) * 768, 768,
             encvt + ((long)h * 512 + col0) * 768, 768, 12,
             acc, lds_a, lds_b);
    EPI256_VARS
    #pragma unroll
    for (int m = 0; m < 8; m++)
        #pragma unroll
        for (int n = 0; n < 4; n++)
            #pragma unroll
            for (int i = 0; i < 4; i++) {
                int row = row0 + ewr + 16 * m + i;   // bL*196+t
                int col = col0 + ewc + 16 * n;       // n in 0..511
                if (row < MC) {
                    float v = fmaxf(acc[m][n][i], 0.f) *
                              bf2f(xs[((long)h * MC + row) * 512 + col]);
                    z[(long)row * 6144 + h * 512 + col] = f2bf(v);
                }
            }
}

// yMLP_raw partial s = z[:, s*1024:(s+1)*1024] @ dec[s...]  (split-K6)
__global__ __launch_bounds__(512, 2) void k_gemm_mlp(const u16* __restrict__ z,
                                                     const u16* __restrict__ dect,
                                                     float* __restrict__ rawK) {
    GEMM256_PROLOGUE
    int row0 = blockIdx.x * 256, col0 = blockIdx.y * 256, s = blockIdx.z;
    gemm256p(z + (long)row0 * 6144 + s * 1024, 6144,
             dect + (long)col0 * 6144 + s * 1024, 6144, 16,
             acc, lds_a, lds_b);
    EPI256_VARS
    float* raw = rawK + (long)s * MC * 768;
    #pragma unroll
    for (int m = 0; m < 8; m++)
        #pragma unroll
        for (int n = 0; n < 4; n++)
            #pragma unroll
            for (int i = 0; i < 4; i++) {
                int row = row0 + ewr + 16 * m + i;
                int col = col0 + ewc + 16 * n;
                if (row < MC)
                    raw[(long)row * 768 + col] = acc[m][n][i];
            }
}

// ---------------------------------------------------------------------------
// per-row LN kernels
// ---------------------------------------------------------------------------
// hn = LN(h) -> hn bf16 (row-major only; hnT built by k_hnT)
__global__ __launch_bounds__(256) void k_ln1(const float* __restrict__ h,
                                             u16* __restrict__ hnb) {
    __shared__ float sm[4];
    int r = blockIdx.x, tid = threadIdx.x;
    const float* p = h + (long)r * 768;
    float x0 = p[tid], x1 = p[tid + 256], x2 = p[tid + 512];
    float mean = block_reduce_sum(x0 + x1 + x2, sm) * (1.f / 768.f);
    float d0 = x0 - mean, d1 = x1 - mean, d2 = x2 - mean;
    float var = block_reduce_sum(d0 * d0 + d1 * d1 + d2 * d2, sm) * (1.f / 768.f);
    float rs = rsqrtf(var + LN_EPS);
    long ro = (long)r * 768;
    hnb[ro + tid] = f2bf(d0 * rs);
    hnb[ro + tid + 256] = f2bf(d1 * rs);
    hnb[ro + tid + 512] = f2bf(d2 * rs);
}

// hnT[b][d][tpad224] = hnb[b*196+t][d], t-pad zero-filled. 32x32 LDS tiles.
__global__ __launch_bounds__(256) void k_hnT(const u16* __restrict__ hnb,
                                             u16* __restrict__ hnT) {
    __shared__ u16 tile[32][33];
    int t0 = blockIdx.x * 32, d0 = blockIdx.y * 32, b = blockIdx.z;
    int i = threadIdx.x >> 5, j = threadIdx.x & 31;
    #pragma unroll
    for (int p = 0; p < 4; p++) {
        int t = t0 + i + p * 8;
        tile[i + p * 8][j] = (t < 196) ? hnb[((long)b * 196 + t) * 768 + d0 + j] : (u16)0;
    }
    __syncthreads();
    #pragma unroll
    for (int p = 0; p < 4; p++) {
        int dd = i + p * 8;
        hnT[((long)b * 768 + d0 + dd) * 224 + t0 + j] = tile[j][dd];
    }
}

// h = LN(hn + LN(sum of 6 split-K partials))
__global__ __launch_bounds__(256) void k_final_h(const float* __restrict__ rawK,
                                                 const u16* __restrict__ hnb,
                                                 float* __restrict__ h) {
    __shared__ float sm[4];
    const long PS = (long)MC * 768;
    int r = blockIdx.x, tid = threadIdx.x;
    const u16* hp = hnb + (long)r * 768;
    float y0 = 0.f, y1 = 0.f, y2 = 0.f;
    #pragma unroll
    for (int s2 = 0; s2 < 6; ++s2) {
        const float* rp = rawK + s2 * PS + (long)r * 768;
        y0 += rp[tid]; y1 += rp[tid + 256]; y2 += rp[tid + 512];
    }
    float mean = block_reduce_sum(y0 + y1 + y2, sm) * (1.f / 768.f);
    float d0 = y0 - mean, d1 = y1 - mean, d2 = y2 - mean;
    float var = block_reduce_sum(d0 * d0 + d1 * d1 + d2 * d2, sm) * (1.f / 768.f);
    float rs = rsqrtf(var + LN_EPS);
    float s0 = bf2f(hp[tid]) + d0 * rs;
    float s1 = bf2f(hp[tid + 256]) + d1 * rs;
    float s2v = bf2f(hp[tid + 512]) + d2 * rs;
    mean = block_reduce_sum(s0 + s1 + s2v, sm) * (1.f / 768.f);
    d0 = s0 - mean; d1 = s1 - mean; d2 = s2v - mean;
    var = block_reduce_sum(d0 * d0 + d1 * d1 + d2 * d2, sm) * (1.f / 768.f);
    rs = rsqrtf(var + LN_EPS);
    long ro = (long)r * 768;
    h[ro + tid] = d0 * rs; h[ro + tid + 256] = d1 * rs; h[ro + tid + 512] = d2 * rs;
}

// pool stage 1: partial sums over 14-row groups -> part[b][g][768]
__global__ __launch_bounds__(256) void k_pool1(const float* __restrict__ h,
                                               float* __restrict__ part) {
    int g = blockIdx.x, b = blockIdx.y, tid = threadIdx.x;
    const float* base = h + ((long)b * 196 + g * 14) * 768;
    float a0 = 0.f, a1 = 0.f, a2 = 0.f;
    for (int t = 0; t < 14; t++) {
        const float* p = base + (long)t * 768;
        a0 += p[tid]; a1 += p[tid + 256]; a2 += p[tid + 512];
    }
    float* pp = part + ((long)b * 14 + g) * 768;
    pp[tid] = a0; pp[tid + 256] = a1; pp[tid + 512] = a2;
}

// pool stage 2: pooled = LN(sum(part)/196)
__global__ __launch_bounds__(256) void k_pool2(const float* __restrict__ part,
                                               float* __restrict__ pooled) {
    __shared__ float sm[4];
    int b = blockIdx.x, tid = threadIdx.x;
    const float* pp = part + (long)b * 14 * 768;
    float a0 = 0.f, a1 = 0.f, a2 = 0.f;
    for (int g = 0; g < 14; g++) {
        a0 += pp[g * 768 + tid]; a1 += pp[g * 768 + tid + 256]; a2 += pp[g * 768 + tid + 512];
    }
    a0 *= (1.f / 196.f); a1 *= (1.f / 196.f); a2 *= (1.f / 196.f);
    float mean = block_reduce_sum(a0 + a1 + a2, sm) * (1.f / 768.f);
    float d0 = a0 - mean, d1 = a1 - mean, d2 = a2 - mean;
    float var = block_reduce_sum(d0 * d0 + d1 * d1 + d2 * d2, sm) * (1.f / 768.f);
    float rs = rsqrtf(var + LN_EPS);
    pooled[(long)b * 768 + tid] = d0 * rs;
    pooled[(long)b * 768 + tid + 256] = d1 * rs;
    pooled[(long)b * 768 + tid + 512] = d2 * rs;
}

// out = pooled @ head_w^T + head_b.  grid (250, 64): wave w -> col 4*bx+w.
__global__ __launch_bounds__(256) void k_head(const float* __restrict__ pooled,
                                              const float* __restrict__ hw,
                                              const float* __restrict__ hb,
                                              float* __restrict__ out) {
    __shared__ float pr[768];
    int b = blockIdx.y, tid = threadIdx.x;
    pr[tid] = pooled[(long)b * 768 + tid];
    pr[tid + 256] = pooled[(long)b * 768 + tid + 256];
    pr[tid + 512] = pooled[(long)b * 768 + tid + 512];
    __syncthreads();
    int c = blockIdx.x * 4 + (tid >> 6);
    int lane = tid & 63;
    const float* wrow = hw + (long)c * 768;
    float acc = 0.f;
    #pragma unroll
    for (int k = 0; k < 768; k += 64) acc += pr[k + lane] * wrow[k + lane];
    #pragma unroll
    for (int o = 32; o; o >>= 1) acc += __shfl_xor(acc, o);
    if (lane == 0) out[(long)b * 1000 + c] = acc + hb[c];
}

// ---------------------------------------------------------------------------
extern "C" void kernel_launch(void* const* d_in, const int* in_sizes, int n_in,
                              void* d_out, int out_size, void* d_ws, size_t ws_size,
                              hipStream_t stream) {
    const float* x     = (const float*)d_in[0];
    const float* convw = (const float*)d_in[1];
    const float* convb = (const float*)d_in[2];
    const float* pe    = (const float*)d_in[3];
    const float* enc   = (const float*)d_in[4];
    const float* encv  = (const float*)d_in[5];
    const float* dec   = (const float*)d_in[6];
    const float* freqs = (const float*)d_in[7];
    const float* hw    = (const float*)d_in[8];
    const float* hbias = (const float*)d_in[9];
    float* out = (float*)d_out;

    char* W = (char*)d_ws;
    size_t off = 0;
    auto ALLOC = [&](size_t bytes) {
        size_t o = off;
        off += (bytes + 255) & ~(size_t)255;
        return o;
    };
    // persistent
    float* bh    = (float*)(W + ALLOC(38535168));            // h f32 (12544x768)
    u16*   bhnb  = (u16*)  (W + ALLOC(19267584 + 524288));   // hn bf16 (+256-tile edge slack)
    u16*   bhnT  = (u16*)  (W + ALLOC(22020096));            // hn^T bf16 (64,768,224)
    u16*   benc  = (u16*)  (W + ALLOC(9437184));             // enc^T  (12,512,768)
    u16*   bencv = (u16*)  (W + ALLOC(9437184));             // encv^T
    u16*   bdec  = (u16*)  (W + ALLOC(9437184));             // dec^T  (768,6144)
    float* btc   = (float*)(W + ALLOC(401408));              // cos (196,512)
    float* bts   = (float*)(W + ALLOC(401408));              // sin
    float* bpool = (float*)(W + ALLOC(196608));              // pooled (64,768)
    float* bpart = (float*)(W + ALLOC(2752512));             // pool partials (64,14,768)
    // chunk regions (+slack for masked edge-tile overreads: 192 rows x lda)
    char*  R1    = (char*) (W + ALLOC(38535168 + 4194304));  // qr / z (z edge: 192*12288B)
    char*  R2    = (char*) (W + ALLOC(57802752 + 524288));   // ykv / rawK (+setup patches)
    char*  R3    = (char*) (W + ALLOC(38535168 + 524288));   // xs (+setup conv_w)
    (void)ws_size; (void)in_sizes; (void)n_in; (void)out_size;
    // total ~252 MiB

    u16*   bap  = (u16*)R2;    // setup: packed patches (18.4M)
    u16*   bcw  = (u16*)R3;    // setup: conv_w bf16 (1.2M)
    u16*   qr   = (u16*)R1;    // per-chunk head-major (192hb,196,512)
    u16*   z    = (u16*)R1;    // (3136,6144)
    u16*   ykv  = (u16*)R2;    // head-major (192hb,196,768)
    float* rawK = (float*)R2;  // yMLP split-K partials 6x(3136,768) f32 = 57.8MB
    u16*   xs   = (u16*)R3;    // head-major (192hb,196,512)

    // ---- setup ----
    k_pack_patches<<<37632, 256, 0, stream>>>(x, bap);
    k_cast<<<2304, 256, 0, stream>>>(convw, bcw, 768 * 768);
    k_gemm_tokens<<<dim3(49, 3), 512, 0, stream>>>(bap, bcw, convb, pe, bh);
    k_transpose_cast<<<dim3(16, 24, 12), 256, 0, stream>>>(enc, benc, 768, 512);
    k_transpose_cast<<<dim3(16, 24, 12), 256, 0, stream>>>(encv, bencv, 768, 512);
    k_transpose_cast<<<dim3(24, 192, 1), 256, 0, stream>>>(dec, bdec, 6144, 768);
    k_rope_tab<<<392, 256, 0, stream>>>(freqs, btc, bts);

    // ---- 6 shared-weight layers, 4 chunks of 16 images each ----
    for (int L = 0; L < 6; ++L) {
        k_ln1<<<12544, 256, 0, stream>>>(bh, bhnb);
        k_hnT<<<dim3(7, 24, 64), 256, 0, stream>>>(bhnb, bhnT);
        for (int c = 0; c < 4; ++c) {
            long r0 = (long)c * MC;                    // chunk row offset
            k_gemm_xs<<<dim3(13, 24), 512, 0, stream>>>(
                bhnb + r0 * 768, benc, btc, bts, xs, qr);
            k_attn<<<dim3(2, 192), 256, 0, stream>>>(
                qr, bhnT + (long)c * 16 * 768 * 224, ykv);
            k_ln_ykv<<<37632, 256, 0, stream>>>(ykv);
            k_gemm_ys<<<dim3(13, 2, 12), 512, 0, stream>>>(ykv, bencv, xs, z);
            k_gemm_mlp<<<dim3(13, 3, 6), 512, 0, stream>>>(z, bdec, rawK);
            k_final_h<<<MC, 256, 0, stream>>>(rawK, bhnb + r0 * 768, bh + r0 * 768);
        }
    }

    // ---- head ----
    k_pool1<<<dim3(14, 64), 256, 0, stream>>>(bh, bpart);
    k_pool2<<<64, 256, 0, stream>>>(bpart, bpool);
    k_head<<<dim3(250, 64), 256, 0, stream>>>(bpool, hw, hbias, out);
}

// Round 4
// 6879.951 us; speedup vs baseline: 1.2919x; 1.2553x over previous
//
#include <hip/hip_runtime.h>
#include <hip/hip_bf16.h>

// ============================================================================
// VisionBDHv2 forward, MI355X (gfx950). Round 11.
// R7: 7775us (128x128 BK=64 2-barrier core, 5 blk/CU TLP) -- PROVEN BASELINE.
// R8-R10: 256x256 variants all regressed/flat (~2600cyc/phase regardless of
//   schedule) -> abandoned. Real signal: ys epilogue moves 77MB scalar
//   (xs read + z write) vs ~57MB GEMM A traffic; K=768 can't amortize it.
// R11 = R7 core +:
//   1) LDS-bounce vectorized epilogues for all 4 GEMMs (acc -> 32KB LDS tile
//      -> coalesced 16B vector ld/st; in-place TU slots, thread-owned 1:1).
//   2) k_ln_ykv DELETED: ykv rows have ~0 mean (P @ LN rows), so
//      LN(raw)@W == rs*(raw@W - mu*colsum). attn epilogue emits per-row
//      (mu,rs) via its existing part[]+shfl machinery; ys applies the fold.
//   3) per-layer k_ln1 DELETED: LN(LN(x))~=LN(x) (unit-var input, err ~5e-6).
//      k_final_h writes hnb bf16 in-place; pooling reads hnb. bh f32 only
//      used once at setup (tokens -> ln1 -> hnb).
// ============================================================================

typedef short bf16x8 __attribute__((ext_vector_type(8)));
typedef float f32x4 __attribute__((ext_vector_type(4)));
typedef unsigned short u16;

#define LN_EPS 1e-5f
#define SM_SCALE 0.044194173824159216f  /* 1/sqrt(512) */
#define TWO_PI 6.283185307179586f
#define MC 3136                          /* rows per chunk = 16*196 */

typedef __attribute__((address_space(3))) unsigned char* as3p;
typedef const __attribute__((address_space(1))) unsigned char* as1p;

__device__ __forceinline__ void gload16(const u16* g, u16* l) {
    __builtin_amdgcn_global_load_lds((as1p)(const void*)g, (as3p)(void*)l, 16, 0, 0);
}

__device__ __forceinline__ u16 f2bf(float f) {
    __hip_bfloat16 h = __float2bfloat16(f);
    return *reinterpret_cast<u16*>(&h);
}
__device__ __forceinline__ float bf2f(u16 u) {
    return __uint_as_float(((unsigned)u) << 16);
}

// ---------------------------------------------------------------------------
// block reductions (256 threads, 4 waves)
// ---------------------------------------------------------------------------
__device__ __forceinline__ float block_reduce_sum(float v, float* sm) {
    #pragma unroll
    for (int o = 32; o; o >>= 1) v += __shfl_xor(v, o);
    if ((threadIdx.x & 63) == 0) sm[threadIdx.x >> 6] = v;
    __syncthreads();
    float r = sm[0] + sm[1] + sm[2] + sm[3];
    __syncthreads();
    return r;
}

// ---------------------------------------------------------------------------
// GEMM core (R7 gemm_core64, verbatim): BK=64, swizzled, 128x128 tile,
// 4 waves (2x2). LDS [128][64] u16 per operand; physical slot s holds
// logical col-slot s^(row&7). Staged via global_load_lds with pre-swizzled
// global source (linear LDS dest). ds_read applies same XOR. C/D: elem i ->
// row (lane>>4)*4+i, col lane&15.
// ---------------------------------------------------------------------------
__device__ __forceinline__ void gemm_core64(const u16* __restrict__ A, int lda,
                                            const u16* __restrict__ Bt, int ldb,
                                            int ksteps, f32x4 acc[4][4],
                                            u16* lds_a, u16* lds_b) {
    const int tid = threadIdx.x;
    const int lane = tid & 63;
    const int wave = tid >> 6;
    const int wr = (wave >> 1) * 64;
    const int wc = (wave & 1) * 64;
    const int lr = lane & 15;
    const int lg = lane >> 4;            // logical k-slot base (0..3)
    const int rx = lr & 7;               // row&7 for this lane's fragment rows
    const int srow = tid >> 3;           // staging row within 32-row group
    const int gslot = (tid & 7) ^ (srow & 7);  // pre-swizzled global col slot
    const u16* ga = A + (long)srow * lda + gslot * 8;
    const u16* gb = Bt + (long)srow * ldb + gslot * 8;
    u16* la = lds_a + tid * 8;           // linear dest: row srow, slot tid&7
    u16* lb = lds_b + tid * 8;
    for (int k0 = 0; k0 < ksteps; ++k0) {
        __syncthreads();                 // prior iteration's reads done
        #pragma unroll
        for (int j = 0; j < 4; ++j) {    // 32-row groups (row&7 invariant)
            gload16(ga + (long)(j * 32) * lda, la + j * 2048);
            gload16(gb + (long)(j * 32) * ldb, lb + j * 2048);
        }
        ga += 64; gb += 64;
        __syncthreads();                 // drains vmcnt(0) before barrier
        bf16x8 af[2][4], bfr[2][4];
        #pragma unroll
        for (int kk = 0; kk < 2; ++kk) {
            const int ps = ((lg + kk * 4) ^ rx) * 8;   // physical elem offset
            #pragma unroll
            for (int m = 0; m < 4; m++)
                af[kk][m] = *(const bf16x8*)&lds_a[(wr + 16 * m + lr) * 64 + ps];
            #pragma unroll
            for (int n = 0; n < 4; n++)
                bfr[kk][n] = *(const bf16x8*)&lds_b[(wc + 16 * n + lr) * 64 + ps];
        }
        #pragma unroll
        for (int kk = 0; kk < 2; ++kk)
            #pragma unroll
            for (int m = 0; m < 4; m++)
                #pragma unroll
                for (int n = 0; n < 4; n++)
                    acc[m][n] = __builtin_amdgcn_mfma_f32_16x16x32_bf16(
                        af[kk][m], bfr[kk][n], acc[m][n], 0, 0, 0);
    }
}

// merged 32KB LDS: gemm uses [lds_a | lds_b]; epilogue reuses as one tile
// (TU u16[128][128] or TF f32[64][128]).
#define GEMM64_PROLOGUE                                 \
    __shared__ alignas(16) u16 lds_ab[2 * 128 * 64];    \
    u16* lds_a = lds_ab;                                \
    u16* lds_b = lds_ab + 128 * 64;                     \
    f32x4 acc[4][4];                                    \
    _Pragma("unroll")                                   \
    for (int m = 0; m < 4; m++)                         \
        _Pragma("unroll")                               \
        for (int n = 0; n < 4; n++)                     \
            acc[m][n] = (f32x4){0.f, 0.f, 0.f, 0.f};

#define EPI_VARS                                        \
    const int lane = threadIdx.x & 63;                  \
    const int wave = threadIdx.x >> 6;                  \
    const int ewr = (wave >> 1) * 64 + (lane >> 4) * 4; \
    const int ewc = (wave & 1) * 64 + (lane & 15);

// ---------------------------------------------------------------------------
// GEMM core v2 (BK=32, linear, 256 threads) — used by k_attn only.
// ---------------------------------------------------------------------------
__device__ __forceinline__ void gemm_core(const u16* __restrict__ A, int lda,
                                          const u16* __restrict__ Bt, int ldb,
                                          int ksteps, f32x4 acc[4][4],
                                          u16* lds_a, u16* lds_b) {
    const int tid = threadIdx.x;
    const int lane = tid & 63;
    const int wave = tid >> 6;
    const int wr = (wave >> 1) * 64;
    const int wc = (wave & 1) * 64;
    const int lr = lane & 15;
    const int lk = (lane >> 4) * 8;
    const int srow = tid >> 2;
    const int scol = (tid & 3) * 8;
    const u16* ga = A + (long)srow * lda + scol;
    const u16* gb = Bt + (long)srow * ldb + scol;
    const long ha = (long)64 * lda;
    const long hb = (long)64 * ldb;
    u16* la = lds_a + tid * 8;
    u16* lb = lds_b + tid * 8;
    for (int k0 = 0; k0 < ksteps; ++k0) {
        __syncthreads();
        gload16(ga, la);
        gload16(ga + ha, la + 2048);
        gload16(gb, lb);
        gload16(gb + hb, lb + 2048);
        ga += 32; gb += 32;
        __syncthreads();
        bf16x8 af[4], bfr[4];
        #pragma unroll
        for (int m = 0; m < 4; m++)
            af[m] = *(const bf16x8*)&lds_a[(wr + 16 * m + lr) * 32 + lk];
        #pragma unroll
        for (int n = 0; n < 4; n++)
            bfr[n] = *(const bf16x8*)&lds_b[(wc + 16 * n + lr) * 32 + lk];
        #pragma unroll
        for (int m = 0; m < 4; m++)
            #pragma unroll
            for (int n = 0; n < 4; n++)
                acc[m][n] = __builtin_amdgcn_mfma_f32_16x16x32_bf16(af[m], bfr[n], acc[m][n], 0, 0, 0);
    }
}

// ---------------------------------------------------------------------------
// setup kernels
// ---------------------------------------------------------------------------
__global__ __launch_bounds__(256) void k_pack_patches(const float* __restrict__ x,
                                                      u16* __restrict__ ap) {
    int idx = blockIdx.x * 256 + threadIdx.x;           // < 12544*768
    int r = idx / 768, k = idx - r * 768;
    int b = r / 196, t = r - b * 196;
    int hp = t / 14, wp = t - hp * 14;
    int c = k >> 8, rem = k & 255, p = rem >> 4, q = rem & 15;
    long src = ((long)(b * 3 + c) * 224 + hp * 16 + p) * 224 + wp * 16 + q;
    ap[idx] = f2bf(x[src]);
}

__global__ __launch_bounds__(256) void k_cast(const float* __restrict__ s,
                                              u16* __restrict__ d, int n) {
    int i = blockIdx.x * 256 + threadIdx.x;
    if (i < n) d[i] = f2bf(s[i]);
}

// src (batch, R, C) f32 -> dst (batch, C, R) bf16
__global__ __launch_bounds__(256) void k_transpose_cast(const float* __restrict__ src,
                                                        u16* __restrict__ dst,
                                                        int R, int C) {
    __shared__ float tile[32][33];
    int c0 = blockIdx.x * 32, r0 = blockIdx.y * 32;
    long base = (long)blockIdx.z * R * C;
    int i = threadIdx.x >> 5, j = threadIdx.x & 31;
    #pragma unroll
    for (int p = 0; p < 4; p++) {
        int rr = i + p * 8;
        tile[rr][j] = src[base + (long)(r0 + rr) * C + c0 + j];
    }
    __syncthreads();
    #pragma unroll
    for (int p = 0; p < 4; p++) {
        int rr = i + p * 8;
        dst[base + (long)(c0 + rr) * R + r0 + j] = f2bf(tile[j][rr]);
    }
}

__global__ __launch_bounds__(256) void k_rope_tab(const float* __restrict__ freqs,
                                                  float* __restrict__ tc,
                                                  float* __restrict__ ts) {
    int idx = blockIdx.x * 256 + threadIdx.x;           // < 196*512
    int t = idx >> 9, n = idx & 511;
    float ph = (float)t * freqs[n];
    ph = (ph - floorf(ph)) * TWO_PI;
    tc[idx] = cosf(ph);
    ts[idx] = sinf(ph);
}

// colsum[h][c] = sum_d encv[h][d][c]  (from f32 encv, coalesced in c)
__global__ __launch_bounds__(256) void k_colsum(const float* __restrict__ encv,
                                                float* __restrict__ cs) {
    int h = blockIdx.y, c = blockIdx.x * 256 + threadIdx.x;   // grid (2,12)
    const float* base = encv + (long)h * 768 * 512 + c;
    float a = 0.f;
    for (int d = 0; d < 768; d++) a += base[(long)d * 512];
    cs[h * 512 + c] = a;
}

// ---------------------------------------------------------------------------
// GEMM kernels (R7 core + LDS-bounce epilogues)
// ---------------------------------------------------------------------------
// tokens = patches @ convw^T + bias + pos_embed -> h   (M=12544,K=768,N=768)
__global__ __launch_bounds__(256) void k_gemm_tokens(const u16* __restrict__ ap,
                                                     const u16* __restrict__ bw,
                                                     const float* __restrict__ cb,
                                                     const float* __restrict__ pe,
                                                     float* __restrict__ hout) {
    GEMM64_PROLOGUE
    int row0 = blockIdx.x * 128, col0 = blockIdx.y * 128;
    gemm_core64(ap + (long)row0 * 768, 768, bw + (long)col0 * 768, 768, 12, acc, lds_a, lds_b);
    EPI_VARS
    const int tid = threadIdx.x;
    float* TF = (float*)lds_ab;          // [64][128] f32, two half-passes
    #pragma unroll
    for (int hf = 0; hf < 2; ++hf) {
        __syncthreads();
        if ((ewr >> 6) == hf) {
            #pragma unroll
            for (int m = 0; m < 4; m++)
                #pragma unroll
                for (int n = 0; n < 4; n++)
                    #pragma unroll
                    for (int i = 0; i < 4; i++) {
                        int row = row0 + ewr + 16 * m + i;
                        int col = col0 + ewc + 16 * n;
                        int t = row % 196;
                        TF[(ewr - hf * 64 + 16 * m + i) * 128 + ewc + 16 * n] =
                            acc[m][n][i] + cb[col] + pe[t * 768 + col];
                    }
        }
        __syncthreads();
        #pragma unroll
        for (int q = 0; q < 8; ++q) {
            int chunk = tid + q * 256;   // 64 rows x 32 chunks (16B=4 f32)
            int r = chunk >> 5, c = chunk & 31;
            *(f32x4*)&hout[(long)(row0 + hf * 64 + r) * 768 + col0 + c * 4] =
                *(f32x4*)&TF[r * 128 + c * 4];
        }
    }
}

// chunk: x_sparse = relu(hn@enc); qr = rope(x_sparse)  (M=3136 masked, N=6144)
// xs/qr written HEAD-MAJOR: [(head*16+bL)*196 + t][512]
__global__ __launch_bounds__(256) void k_gemm_xs(const u16* __restrict__ hnb,
                                                 const u16* __restrict__ enct,
                                                 const float* __restrict__ tc,
                                                 const float* __restrict__ tsn,
                                                 u16* __restrict__ xs,
                                                 u16* __restrict__ qr) {
    GEMM64_PROLOGUE
    // XCD swizzle: grid (25,48) -> 1200 wgs, q=150
    int p = blockIdx.x + 25 * blockIdx.y;
    int w = (p & 7) * 150 + (p >> 3);
    int row0 = (w % 25) * 128, col0 = (w / 25) * 128;
    int head = col0 >> 9, nn0 = col0 & 511;
    gemm_core64(hnb + (long)row0 * 768, 768,
                enct + ((long)head * 512 + nn0) * 768, 768, 12, acc, lds_a, lds_b);
    EPI_VARS
    const int tid = threadIdx.x;
    u16* TU = lds_ab;                    // [128][128] u16
    // ---- pass 1: xs = relu(acc) ----
    __syncthreads();
    #pragma unroll
    for (int m = 0; m < 4; m++)
        #pragma unroll
        for (int n = 0; n < 4; n++)
            #pragma unroll
            for (int i = 0; i < 4; i++)
                TU[(ewr + 16 * m + i) * 128 + ewc + 16 * n] =
                    f2bf(fmaxf(acc[m][n][i], 0.f));
    __syncthreads();
    #pragma unroll
    for (int q = 0; q < 8; ++q) {
        int chunk = tid + q * 256;       // 128 rows x 16 chunks (16B=8 u16)
        int r = chunk >> 4, c = chunk & 15;
        int row = row0 + r;
        if (row < MC)
            *(bf16x8*)&xs[((long)head * MC + row) * 512 + nn0 + c * 8] =
                *(bf16x8*)&TU[r * 128 + c * 8];
    }
    __syncthreads();
    // ---- pass 2: qr = rope(xs) ----
    #pragma unroll
    for (int m = 0; m < 4; m++)
        #pragma unroll
        for (int n = 0; n < 4; n++)
            #pragma unroll
            for (int i = 0; i < 4; i++) {
                int row = row0 + ewr + 16 * m + i;
                float v = fmaxf(acc[m][n][i], 0.f);
                float pp = __shfl_xor(v, 1);       // all lanes participate
                if (row < MC) {
                    int t = row % 196;
                    int nn = nn0 + ewc + 16 * n;
                    float cs = tc[t * 512 + nn], sn = tsn[t * 512 + nn];
                    float rot = (nn & 1) ? pp : -pp;
                    TU[(ewr + 16 * m + i) * 128 + ewc + 16 * n] =
                        f2bf(v * cs + rot * sn);
                }
            }
    __syncthreads();
    #pragma unroll
    for (int q = 0; q < 8; ++q) {
        int chunk = tid + q * 256;
        int r = chunk >> 4, c = chunk & 15;
        int row = row0 + r;
        if (row < MC)
            *(bf16x8*)&qr[((long)head * MC + row) * 512 + nn0 + c * 8] =
                *(bf16x8*)&TU[r * 128 + c * 8];
    }
}

// ---------------------------------------------------------------------------
// Fused attention + ykv row stats (mu, rs) for the ys LN-fold.
// One block per (row-tile 128, bh'=h*16+bL). Scores in regs, in-register
// softmax, P bf16 in LDS [128][232], PV over 6 col-tiles. After PV, per-row
// sum/sumsq accumulated in part[] (reused), stats written as float2.
// ---------------------------------------------------------------------------
__global__ __launch_bounds__(256) void k_attn(const u16* __restrict__ qr,
                                              const u16* __restrict__ hnT,
                                              u16* __restrict__ ykv,
                                              float* __restrict__ stats) {
    __shared__ alignas(16) u16 lds_a[128 * 32];
    __shared__ alignas(16) u16 lds_b[128 * 32];
    __shared__ alignas(16) u16 Pl[128 * 232];
    __shared__ float part[2][128][2];    // [max|sum][row][wave-col-half]
    const int tid = threadIdx.x, lane = tid & 63, wave = tid >> 6;
    const int wr = (wave >> 1) * 64, wc = (wave & 1) * 64;
    const int lr = lane & 15, lk = (lane >> 4) * 8;
    const int row0 = blockIdx.x * 128, bh = blockIdx.y;  // bh = h*16+bL
    const int bL = bh & 15;
    const u16* qbase = qr + (long)bh * 196 * 512;

    f32x4 acc0[4][4], acc1[4][4];
    #pragma unroll
    for (int m = 0; m < 4; m++)
        #pragma unroll
        for (int n = 0; n < 4; n++) {
            acc0[m][n] = (f32x4){0.f, 0.f, 0.f, 0.f};
            acc1[m][n] = (f32x4){0.f, 0.f, 0.f, 0.f};
        }
    // scores: S[row, col] = Q[row0+row] . Q[col], two 128-col tiles (K=512)
    gemm_core(qbase + (long)row0 * 512, 512, qbase, 512, 16, acc0, lds_a, lds_b);
    gemm_core(qbase + (long)row0 * 512, 512, qbase + 128 * 512, 512, 16, acc1, lds_a, lds_b);

    // ---- softmax over cols (valid < 196), scale applied inside exp ----
    const int rb = wr + (lane >> 4) * 4;
    #pragma unroll
    for (int m = 0; m < 4; m++)
        #pragma unroll
        for (int i = 0; i < 4; i++) {
            float mx = -1e30f;
            #pragma unroll
            for (int n = 0; n < 4; n++) {
                int c0 = wc + 16 * n + lr;
                if (c0 < 196) mx = fmaxf(mx, acc0[m][n][i]);
                if (c0 + 128 < 196) mx = fmaxf(mx, acc1[m][n][i]);
            }
            #pragma unroll
            for (int o = 1; o < 16; o <<= 1) mx = fmaxf(mx, __shfl_xor(mx, o));
            if (lr == 0) part[0][rb + 16 * m + i][wave & 1] = mx;
        }
    __syncthreads();
    #pragma unroll
    for (int m = 0; m < 4; m++)
        #pragma unroll
        for (int i = 0; i < 4; i++) {
            int row = rb + 16 * m + i;
            float rmx = fmaxf(part[0][row][0], part[0][row][1]);
            float s = 0.f;
            #pragma unroll
            for (int n = 0; n < 4; n++) {
                int c0 = wc + 16 * n + lr;
                float e0 = (c0 < 196) ? __expf((acc0[m][n][i] - rmx) * SM_SCALE) : 0.f;
                float e1 = (c0 + 128 < 196) ? __expf((acc1[m][n][i] - rmx) * SM_SCALE) : 0.f;
                acc0[m][n][i] = e0; acc1[m][n][i] = e1;
                s += e0 + e1;
            }
            #pragma unroll
            for (int o = 1; o < 16; o <<= 1) s += __shfl_xor(s, o);
            if (lr == 0) part[1][row][wave & 1] = s;
        }
    __syncthreads();
    #pragma unroll
    for (int m = 0; m < 4; m++)
        #pragma unroll
        for (int i = 0; i < 4; i++) {
            int row = rb + 16 * m + i;
            float inv = 1.f / (part[1][row][0] + part[1][row][1]);
            #pragma unroll
            for (int n = 0; n < 4; n++) {
                int c0 = wc + 16 * n + lr;
                Pl[row * 232 + c0] = f2bf(acc0[m][n][i] * inv);
                if (c0 + 128 < 224)
                    Pl[row * 232 + c0 + 128] = f2bf(acc1[m][n][i] * inv);
            }
        }
    // part[] now free: zero it for ykv row-stats accumulation
    __syncthreads();
    { float* pf = &part[0][0][0]; pf[tid] = 0.f; pf[tid + 256] = 0.f; }
    // ---- PV: O[row, d] = sum_s P[row,s] * hnT[d][s], 6 col-tiles, K=224 ----
    const int srow = tid >> 2, scol = (tid & 3) * 8;
    for (int cd = 0; cd < 6; ++cd) {
        const u16* Bt = hnT + ((long)bL * 768 + cd * 128) * 224;
        f32x4 acc[4][4];
        #pragma unroll
        for (int m = 0; m < 4; m++)
            #pragma unroll
            for (int n = 0; n < 4; n++) acc[m][n] = (f32x4){0.f, 0.f, 0.f, 0.f};
        for (int k0 = 0; k0 < 7; ++k0) {
            __syncthreads();
            gload16(Bt + (long)srow * 224 + k0 * 32 + scol, lds_b + tid * 8);
            gload16(Bt + (long)(srow + 64) * 224 + k0 * 32 + scol, lds_b + 2048 + tid * 8);
            __syncthreads();
            bf16x8 af[4], bfr[4];
            #pragma unroll
            for (int m = 0; m < 4; m++)
                af[m] = *(const bf16x8*)&Pl[(wr + 16 * m + lr) * 232 + k0 * 32 + lk];
            #pragma unroll
            for (int n = 0; n < 4; n++)
                bfr[n] = *(const bf16x8*)&lds_b[(wc + 16 * n + lr) * 32 + lk];
            #pragma unroll
            for (int m = 0; m < 4; m++)
                #pragma unroll
                for (int n = 0; n < 4; n++)
                    acc[m][n] = __builtin_amdgcn_mfma_f32_16x16x32_bf16(af[m], bfr[n], acc[m][n], 0, 0, 0);
        }
        // row-stats partials for this 128-col slab (per-thread slots, no race)
        #pragma unroll
        for (int m = 0; m < 4; m++)
            #pragma unroll
            for (int i = 0; i < 4; i++) {
                float s = acc[m][0][i] + acc[m][1][i] + acc[m][2][i] + acc[m][3][i];
                float q2 = acc[m][0][i] * acc[m][0][i] + acc[m][1][i] * acc[m][1][i] +
                           acc[m][2][i] * acc[m][2][i] + acc[m][3][i] * acc[m][3][i];
                #pragma unroll
                for (int o = 1; o < 16; o <<= 1) {
                    s += __shfl_xor(s, o);
                    q2 += __shfl_xor(q2, o);
                }
                if (lr == 0) {
                    part[0][rb + 16 * m + i][wave & 1] += s;
                    part[1][rb + 16 * m + i][wave & 1] += q2;
                }
            }
        EPI_VARS
        #pragma unroll
        for (int m = 0; m < 4; m++)
            #pragma unroll
            for (int n = 0; n < 4; n++)
                #pragma unroll
                for (int i = 0; i < 4; i++) {
                    int trow = row0 + ewr + 16 * m + i;
                    if (trow < 196)
                        ykv[((long)bh * 196 + trow) * 768 + cd * 128 + ewc + 16 * n] =
                            f2bf(acc[m][n][i]);
                }
    }
    // finalize row stats
    __syncthreads();
    if (tid < 128) {
        int trow = row0 + tid;
        if (trow < 196) {
            float s = part[0][tid][0] + part[0][tid][1];
            float q2 = part[1][tid][0] + part[1][tid][1];
            float mu = s * (1.f / 768.f);
            float var = q2 * (1.f / 768.f) - mu * mu;
            float2 st;
            st.x = mu;
            st.y = rsqrtf(var + LN_EPS);
            *(float2*)&stats[((long)bh * 196 + trow) * 2] = st;
        }
    }
}

// y_sparse = relu(LN(ykv) @ encv) via fold: rs*(acc - mu*colsum);
// z = x_sparse*y_sparse, head-major flatten. grid (25,4,12), swizzled.
__global__ __launch_bounds__(256) void k_gemm_ys(const u16* __restrict__ ykv,
                                                 const u16* __restrict__ encvt,
                                                 const u16* __restrict__ xs,
                                                 const float* __restrict__ stats,
                                                 const float* __restrict__ colsum,
                                                 u16* __restrict__ z) {
    GEMM64_PROLOGUE
    // XCD swizzle: 1200 wgs, q=150
    int p = blockIdx.x + 25 * (blockIdx.y + 4 * blockIdx.z);
    int w = (p & 7) * 150 + (p >> 3);
    int rt = w % 25, rem = w / 25;
    int ct = rem & 3, h = rem >> 2;
    int row0 = rt * 128, col0 = ct * 128;
    gemm_core64(ykv + ((long)h * MC + row0) * 768, 768,
                encvt + ((long)h * 512 + col0) * 768, 768, 12, acc, lds_a, lds_b);
    EPI_VARS
    const int tid = threadIdx.x;
    u16* TU = lds_ab;                    // [128][128]
    // phase A: vector-load xs tile
    __syncthreads();
    #pragma unroll
    for (int q = 0; q < 8; ++q) {
        int chunk = tid + q * 256;
        int r = chunk >> 4, c = chunk & 15;
        *(bf16x8*)&TU[r * 128 + c * 8] =
            *(const bf16x8*)&xs[((long)h * MC + row0 + r) * 512 + col0 + c * 8];
    }
    __syncthreads();
    // phase B: in-place fold+relu+mul (thread-owned slots)
    #pragma unroll
    for (int m = 0; m < 4; m++)
        #pragma unroll
        for (int i = 0; i < 4; i++) {
            int rloc = ewr + 16 * m + i;
            int row = row0 + rloc;
            float mu = 0.f, rs = 0.f;
            if (row < MC) {
                float2 st = *(const float2*)&stats[((long)h * MC + row) * 2];
                mu = st.x; rs = st.y;
            }
            #pragma unroll
            for (int n = 0; n < 4; n++) {
                int cloc = ewc + 16 * n;
                float cs = colsum[h * 512 + col0 + cloc];
                float v = (acc[m][n][i] - mu * cs) * rs;
                v = fmaxf(v, 0.f) * bf2f(TU[rloc * 128 + cloc]);
                TU[rloc * 128 + cloc] = f2bf(v);
            }
        }
    __syncthreads();
    // phase C: vector-store z tile
    #pragma unroll
    for (int q = 0; q < 8; ++q) {
        int chunk = tid + q * 256;
        int r = chunk >> 4, c = chunk & 15;
        int row = row0 + r;
        if (row < MC)
            *(bf16x8*)&z[(long)row * 6144 + h * 512 + col0 + c * 8] =
                *(bf16x8*)&TU[r * 128 + c * 8];
    }
}

// yMLP_raw partial s = z[:, s*1536:(s+1)*1536] @ dec[s...]  (split-K4)
__global__ __launch_bounds__(256) void k_gemm_mlp(const u16* __restrict__ z,
                                                  const u16* __restrict__ dect,
                                                  float* __restrict__ rawK) {
    GEMM64_PROLOGUE
    // XCD swizzle: grid (25,6,4) -> 600 wgs, q=75
    int p = blockIdx.x + 25 * (blockIdx.y + 6 * blockIdx.z);
    int w = (p & 7) * 75 + (p >> 3);
    int row0 = (w % 25) * 128, col0 = ((w / 25) % 6) * 128, s = w / 150;
    gemm_core64(z + (long)row0 * 6144 + s * 1536, 6144,
                dect + (long)col0 * 6144 + s * 1536, 6144, 24, acc, lds_a, lds_b);
    EPI_VARS
    const int tid = threadIdx.x;
    float* TF = (float*)lds_ab;          // [64][128] f32, two half-passes
    float* raw = rawK + (long)s * MC * 768;
    #pragma unroll
    for (int hf = 0; hf < 2; ++hf) {
        __syncthreads();
        if ((ewr >> 6) == hf) {
            #pragma unroll
            for (int m = 0; m < 4; m++)
                #pragma unroll
                for (int n = 0; n < 4; n++)
                    #pragma unroll
                    for (int i = 0; i < 4; i++)
                        TF[(ewr - hf * 64 + 16 * m + i) * 128 + ewc + 16 * n] =
                            acc[m][n][i];
        }
        __syncthreads();
        #pragma unroll
        for (int q = 0; q < 8; ++q) {
            int chunk = tid + q * 256;
            int r = chunk >> 5, c = chunk & 31;
            int row = row0 + hf * 64 + r;
            if (row < MC)
                *(f32x4*)&raw[(long)row * 768 + col0 + c * 4] =
                    *(f32x4*)&TF[r * 128 + c * 4];
        }
    }
}

// ---------------------------------------------------------------------------
// per-row LN kernels
// ---------------------------------------------------------------------------
// hn = LN(h) -> hn bf16 (used ONCE after tokens; later layers skip: LN(LN)~id)
__global__ __launch_bounds__(256) void k_ln1(const float* __restrict__ h,
                                             u16* __restrict__ hnb) {
    __shared__ float sm[4];
    int r = blockIdx.x, tid = threadIdx.x;
    const float* p = h + (long)r * 768;
    float x0 = p[tid], x1 = p[tid + 256], x2 = p[tid + 512];
    float mean = block_reduce_sum(x0 + x1 + x2, sm) * (1.f / 768.f);
    float d0 = x0 - mean, d1 = x1 - mean, d2 = x2 - mean;
    float var = block_reduce_sum(d0 * d0 + d1 * d1 + d2 * d2, sm) * (1.f / 768.f);
    float rs = rsqrtf(var + LN_EPS);
    long ro = (long)r * 768;
    hnb[ro + tid] = f2bf(d0 * rs);
    hnb[ro + tid + 256] = f2bf(d1 * rs);
    hnb[ro + tid + 512] = f2bf(d2 * rs);
}

// hnT[b][d][tpad224] = hnb[b*196+t][d], t-pad zero-filled. 32x32 LDS tiles.
__global__ __launch_bounds__(256) void k_hnT(const u16* __restrict__ hnb,
                                             u16* __restrict__ hnT) {
    __shared__ u16 tile[32][33];
    int t0 = blockIdx.x * 32, d0 = blockIdx.y * 32, b = blockIdx.z;
    int i = threadIdx.x >> 5, j = threadIdx.x & 31;
    #pragma unroll
    for (int p = 0; p < 4; p++) {
        int t = t0 + i + p * 8;
        tile[i + p * 8][j] = (t < 196) ? hnb[((long)b * 196 + t) * 768 + d0 + j] : (u16)0;
    }
    __syncthreads();
    #pragma unroll
    for (int p = 0; p < 4; p++) {
        int dd = i + p * 8;
        hnT[((long)b * 768 + d0 + dd) * 224 + t0 + j] = tile[j][dd];
    }
}

// hnb = LN(hnb + LN(sum of 4 split-K partials))  [in-place: reads first]
__global__ __launch_bounds__(256) void k_final_h(const float* __restrict__ rawK,
                                                 u16* __restrict__ hnb) {
    __shared__ float sm[4];
    const long PS = (long)MC * 768;
    int r = blockIdx.x, tid = threadIdx.x;
    const float* rp = rawK + (long)r * 768;
    u16* hp = hnb + (long)r * 768;
    float y0 = rp[tid] + rp[tid + PS] + rp[tid + 2 * PS] + rp[tid + 3 * PS];
    float y1 = rp[tid + 256] + rp[tid + 256 + PS] + rp[tid + 256 + 2 * PS] + rp[tid + 256 + 3 * PS];
    float y2 = rp[tid + 512] + rp[tid + 512 + PS] + rp[tid + 512 + 2 * PS] + rp[tid + 512 + 3 * PS];
    float h0 = bf2f(hp[tid]), h1 = bf2f(hp[tid + 256]), h2 = bf2f(hp[tid + 512]);
    float mean = block_reduce_sum(y0 + y1 + y2, sm) * (1.f / 768.f);
    float d0 = y0 - mean, d1 = y1 - mean, d2 = y2 - mean;
    float var = block_reduce_sum(d0 * d0 + d1 * d1 + d2 * d2, sm) * (1.f / 768.f);
    float rs = rsqrtf(var + LN_EPS);
    float s0 = h0 + d0 * rs;
    float s1 = h1 + d1 * rs;
    float s2 = h2 + d2 * rs;
    mean = block_reduce_sum(s0 + s1 + s2, sm) * (1.f / 768.f);
    d0 = s0 - mean; d1 = s1 - mean; d2 = s2 - mean;
    var = block_reduce_sum(d0 * d0 + d1 * d1 + d2 * d2, sm) * (1.f / 768.f);
    rs = rsqrtf(var + LN_EPS);
    hp[tid] = f2bf(d0 * rs);
    hp[tid + 256] = f2bf(d1 * rs);
    hp[tid + 512] = f2bf(d2 * rs);
}

// pool stage 1: partial sums over 14-row groups -> part[b][g][768] (bf16 in)
__global__ __launch_bounds__(256) void k_pool1(const u16* __restrict__ hnb,
                                               float* __restrict__ part) {
    int g = blockIdx.x, b = blockIdx.y, tid = threadIdx.x;
    const u16* base = hnb + ((long)b * 196 + g * 14) * 768;
    float a0 = 0.f, a1 = 0.f, a2 = 0.f;
    for (int t = 0; t < 14; t++) {
        const u16* p = base + (long)t * 768;
        a0 += bf2f(p[tid]); a1 += bf2f(p[tid + 256]); a2 += bf2f(p[tid + 512]);
    }
    float* pp = part + ((long)b * 14 + g) * 768;
    pp[tid] = a0; pp[tid + 256] = a1; pp[tid + 512] = a2;
}

// pool stage 2: pooled = LN(sum(part)/196)
__global__ __launch_bounds__(256) void k_pool2(const float* __restrict__ part,
                                               float* __restrict__ pooled) {
    __shared__ float sm[4];
    int b = blockIdx.x, tid = threadIdx.x;
    const float* pp = part + (long)b * 14 * 768;
    float a0 = 0.f, a1 = 0.f, a2 = 0.f;
    for (int g = 0; g < 14; g++) {
        a0 += pp[g * 768 + tid]; a1 += pp[g * 768 + tid + 256]; a2 += pp[g * 768 + tid + 512];
    }
    a0 *= (1.f / 196.f); a1 *= (1.f / 196.f); a2 *= (1.f / 196.f);
    float mean = block_reduce_sum(a0 + a1 + a2, sm) * (1.f / 768.f);
    float d0 = a0 - mean, d1 = a1 - mean, d2 = a2 - mean;
    float var = block_reduce_sum(d0 * d0 + d1 * d1 + d2 * d2, sm) * (1.f / 768.f);
    float rs = rsqrtf(var + LN_EPS);
    pooled[(long)b * 768 + tid] = d0 * rs;
    pooled[(long)b * 768 + tid + 256] = d1 * rs;
    pooled[(long)b * 768 + tid + 512] = d2 * rs;
}

// out = pooled @ head_w^T + head_b.  grid (250, 64): wave w -> col 4*bx+w.
__global__ __launch_bounds__(256) void k_head(const float* __restrict__ pooled,
                                              const float* __restrict__ hw,
                                              const float* __restrict__ hb,
                                              float* __restrict__ out) {
    __shared__ float pr[768];
    int b = blockIdx.y, tid = threadIdx.x;
    pr[tid] = pooled[(long)b * 768 + tid];
    pr[tid + 256] = pooled[(long)b * 768 + tid + 256];
    pr[tid + 512] = pooled[(long)b * 768 + tid + 512];
    __syncthreads();
    int c = blockIdx.x * 4 + (tid >> 6);
    int lane = tid & 63;
    const float* wrow = hw + (long)c * 768;
    float acc = 0.f;
    #pragma unroll
    for (int k = 0; k < 768; k += 64) acc += pr[k + lane] * wrow[k + lane];
    #pragma unroll
    for (int o = 32; o; o >>= 1) acc += __shfl_xor(acc, o);
    if (lane == 0) out[(long)b * 1000 + c] = acc + hb[c];
}

// ---------------------------------------------------------------------------
extern "C" void kernel_launch(void* const* d_in, const int* in_sizes, int n_in,
                              void* d_out, int out_size, void* d_ws, size_t ws_size,
                              hipStream_t stream) {
    const float* x     = (const float*)d_in[0];
    const float* convw = (const float*)d_in[1];
    const float* convb = (const float*)d_in[2];
    const float* pe    = (const float*)d_in[3];
    const float* enc   = (const float*)d_in[4];
    const float* encv  = (const float*)d_in[5];
    const float* dec   = (const float*)d_in[6];
    const float* freqs = (const float*)d_in[7];
    const float* hw    = (const float*)d_in[8];
    const float* hbias = (const float*)d_in[9];
    float* out = (float*)d_out;

    char* W = (char*)d_ws;
    size_t off = 0;
    auto ALLOC = [&](size_t bytes) {
        size_t o = off;
        off += (bytes + 255) & ~(size_t)255;
        return o;
    };
    // persistent
    float* bh    = (float*)(W + ALLOC(38535168));            // h f32 (setup only)
    u16*   bhnb  = (u16*)  (W + ALLOC(19267584 + 524288));   // hn bf16 (+edge slack)
    u16*   bhnT  = (u16*)  (W + ALLOC(22020096));            // hn^T bf16 (64,768,224)
    u16*   benc  = (u16*)  (W + ALLOC(9437184));             // enc^T  (12,512,768)
    u16*   bencv = (u16*)  (W + ALLOC(9437184));             // encv^T
    u16*   bdec  = (u16*)  (W + ALLOC(9437184));             // dec^T  (768,6144)
    float* btc   = (float*)(W + ALLOC(401408));              // cos (196,512)
    float* bts   = (float*)(W + ALLOC(401408));              // sin
    float* bpool = (float*)(W + ALLOC(196608));              // pooled (64,768)
    float* bpart = (float*)(W + ALLOC(2752512));             // pool partials (64,14,768)
    float* bstats= (float*)(W + ALLOC(301056));              // ykv row stats (192*196 x f32x2)
    float* bcs   = (float*)(W + ALLOC(24576));               // encv colsums (12,512)
    // chunk regions (+slack for masked edge-tile overreads)
    char*  R1    = (char*) (W + ALLOC(38535168 + 2097152));  // qr / z
    char*  R2    = (char*) (W + ALLOC(57802752 + 524288));   // ykv / rawK (+setup patches)
    char*  R3    = (char*) (W + ALLOC(38535168 + 524288));   // xs (+setup conv_w)
    (void)ws_size; (void)in_sizes; (void)n_in; (void)out_size;

    u16*   bap  = (u16*)R2;    // setup: packed patches (18.4M)
    u16*   bcw  = (u16*)R3;    // setup: conv_w bf16 (1.2M)
    u16*   qr   = (u16*)R1;    // per-chunk head-major (192hb,196,512)
    u16*   z    = (u16*)R1;    // (3136,6144)
    u16*   ykv  = (u16*)R2;    // head-major (192hb,196,768)
    float* rawK = (float*)R2;  // yMLP split-K partials 4x(3136,768) f32
    u16*   xs   = (u16*)R3;    // head-major (192hb,196,512)

    // ---- setup ----
    k_pack_patches<<<37632, 256, 0, stream>>>(x, bap);
    k_cast<<<2304, 256, 0, stream>>>(convw, bcw, 768 * 768);
    k_gemm_tokens<<<dim3(98, 6), 256, 0, stream>>>(bap, bcw, convb, pe, bh);
    k_transpose_cast<<<dim3(16, 24, 12), 256, 0, stream>>>(enc, benc, 768, 512);
    k_transpose_cast<<<dim3(16, 24, 12), 256, 0, stream>>>(encv, bencv, 768, 512);
    k_transpose_cast<<<dim3(24, 192, 1), 256, 0, stream>>>(dec, bdec, 6144, 768);
    k_rope_tab<<<392, 256, 0, stream>>>(freqs, btc, bts);
    k_colsum<<<dim3(2, 12), 256, 0, stream>>>(encv, bcs);
    k_ln1<<<12544, 256, 0, stream>>>(bh, bhnb);   // once; thereafter LN(LN)~id

    // ---- 6 shared-weight layers, 4 chunks of 16 images each ----
    for (int L = 0; L < 6; ++L) {
        k_hnT<<<dim3(7, 24, 64), 256, 0, stream>>>(bhnb, bhnT);
        for (int c = 0; c < 4; ++c) {
            long r0 = (long)c * MC;                    // chunk row offset
            k_gemm_xs<<<dim3(25, 48), 256, 0, stream>>>(
                bhnb + r0 * 768, benc, btc, bts, xs, qr);
            k_attn<<<dim3(2, 192), 256, 0, stream>>>(
                qr, bhnT + (long)c * 16 * 768 * 224, ykv, bstats);
            k_gemm_ys<<<dim3(25, 4, 12), 256, 0, stream>>>(ykv, bencv, xs, bstats, bcs, z);
            k_gemm_mlp<<<dim3(25, 6, 4), 256, 0, stream>>>(z, bdec, rawK);
            k_final_h<<<MC, 256, 0, stream>>>(rawK, bhnb + r0 * 768);
        }
    }

    // ---- head ----
    k_pool1<<<dim3(14, 64), 256, 0, stream>>>(bhnb, bpart);
    k_pool2<<<64, 256, 0, stream>>>(bpart, bpool);
    k_head<<<dim3(250, 64), 256, 0, stream>>>(bpool, hw, hbias, out);
}